// Round 1
// baseline (2334.665 us; speedup 1.0000x reference)
//
#include <hip/hip_runtime.h>
#include <hip/hip_bf16.h>
#include <math.h>

typedef unsigned int u32;

#define B_ 128
#define S_ 128
#define T_ 127
#define D_ 100
#define QN_ 4
#define SN_ 4
#define KC_ 4
#define RK_ 10
#define NEGV -1000000000.0f

__device__ __forceinline__ float sigmf(float x) { return 1.0f / (1.0f + expf(-x)); }

__device__ __forceinline__ u32 f2bfbits(float x) {
  __hip_bfloat16 h = __float2bfloat16(x);
  unsigned short s;
  __builtin_memcpy(&s, &h, 2);
  return (u32)s;
}

// ---------------------------------------------------------------------------
// Setup (unchanged): transposed f32 weights for phaseA/B; erw fold;
// kw0 scalar; bf16 lane-swizzled weight image (1792 slots x 64 u32 = 256B):
//   [0,300): W_hh1 | [300,600): W_hh2 | [1024,1324): W_ih2 | [1536,1636): W_query
// slot bytes: [sub(4)][k(16 u32)], u32 k packs bf16 cols (sub*25+2k, +2k+1).
// ---------------------------------------------------------------------------
__global__ __launch_bounds__(256) void setupk(
    const float* Er, const float* W_ih1, const float* b_ih1,
    const float* Wagg, const float* W_last, const float* W_key,
    const float* b_query, const float* W_W, const float* W_query,
    const float* W_hh1, const float* W_hh2, const float* W_ih2,
    const float* b_hh1, const float* b_hh2, const float* b_ih2,
    float* wih1aT, float* erw, float* waggT, float* wlastT, float* wkeyT,
    float* scal, u32* wcat16, float* bcat)
{
  int gid = blockIdx.x * blockDim.x + threadIdx.x;
  int gsz = gridDim.x * blockDim.x;

  for (int x = gid; x < 30000; x += gsz) {
    int j = x / 300, i = x % 300;
    wih1aT[j * 300 + i] = W_ih1[i * 200 + j];
  }
  for (int x = gid; x < 600; x += gsz) {
    int r = x / 300, i = x % 300;
    float acc = b_ih1[i];
    for (int j = 0; j < 100; j++) acc += Er[r * 100 + j] * W_ih1[i * 200 + 100 + j];
    erw[x] = acc;
  }
  for (int x = gid; x < 30000; x += gsz) {
    int h = x / 10000, rr = x % 10000, j = rr / 100, i = rr % 100;
    waggT[h * 10000 + j * 100 + i] = Wagg[h * 10000 + i * 100 + j];
  }
  for (int x = gid; x < 10000; x += gsz) {
    int j = x / 100, i = x % 100;
    wlastT[j * 100 + i] = W_last[i * 100 + j];
    wkeyT[j * 100 + i] = W_key[i * 100 + j];
  }
  for (int x = gid; x < 114688; x += gsz) {
    int slot = x / 64, rem = x % 64, sbu = rem / 16, k = rem % 16;
    const float* src = nullptr;
    if (slot < 300)                       src = W_hh1 + (size_t)slot * 100;
    else if (slot < 600)                  src = W_hh2 + (size_t)(slot - 300) * 100;
    else if (slot >= 1024 && slot < 1324) src = W_ih2 + (size_t)(slot - 1024) * 100;
    else if (slot >= 1536 && slot < 1636) src = W_query + (size_t)(slot - 1536) * 100;
    u32 lo = 0, hi = 0;
    if (src) {
      int e0 = 2 * k, e1 = 2 * k + 1;
      if (e0 < 25) lo = f2bfbits(src[sbu * 25 + e0]);
      if (e1 < 25) hi = f2bfbits(src[sbu * 25 + e1]);
    }
    wcat16[x] = (hi << 16) | lo;
  }
  for (int x = gid; x < 1792; x += gsz) {
    float v = 0.f;
    if (x < 300) v = b_hh1[x];
    else if (x < 600) v = b_hh2[x - 300];
    else if (x >= 1024 && x < 1324) v = b_ih2[x - 1024];
    else if (x >= 1536 && x < 1636) v = b_query[x - 1536];
    bcat[x] = v;
  }
  if (gid == 0) {
    float acc = 0.f;  // kw of the all-zero hist state: dot(tanh(b_query), Wk_part)
    for (int i = 0; i < 100; i++) acc += tanhf(b_query[i]) * W_W[100 + i];
    scal[0] = acc;
  }
}

// ---------------------------------------------------------------------------
// Phase A (unchanged): per (b,t) 3-hop aggregate -> gi1[b,t,0:300]
// ---------------------------------------------------------------------------
__global__ __launch_bounds__(256) void phaseA(
    const float* Eq, const float* Ec, const int* question, const int* response, const int* mask,
    const int* qnb, const int* snb,
    const float* wih1aT, const float* erw, const float* waggT, const float* wlastT,
    const float* baggf, const float* blastf, float* gi1_all)
{
  const int t = blockIdx.x, b = blockIdx.y, tid = threadIdx.x;
  __shared__ float e0[100], ne0[100], e1[400], ne1[400];
  __shared__ float e2[1600], ne2[1600], m3[1600];
  __shared__ float sum4[400], sum1[100], emq[100];
  __shared__ int l1[4], l2[16], l3[64];

  const int qt = question[b * S_ + t];
  const int mt = mask[b * S_ + t];
  const int rt = response[b * S_ + t];

  if (mt != 0) {
    if (tid < 4) l1[tid] = qnb[qt * QN_ + tid];
    for (int x = tid; x < 100; x += 256) e0[x] = Eq[(size_t)qt * 100 + x];
    __syncthreads();
    if (tid < 16) l2[tid] = snb[l1[tid >> 2] * SN_ + (tid & 3)];
    for (int x = tid; x < 400; x += 256) e1[x] = Ec[(size_t)l1[x / 100] * 100 + (x % 100)];
    __syncthreads();
    if (tid < 64) l3[tid] = qnb[l2[tid >> 2] * QN_ + (tid & 3)];
    for (int x = tid; x < 1600; x += 256) e2[x] = Eq[(size_t)l2[x / 100] * 100 + (x % 100)];
    __syncthreads();
    for (int x = tid; x < 1600; x += 256) {
      int r = x / 100, j = x % 100;
      const int* lr = l3 + r * 4;
      float s = Ec[(size_t)lr[0] * 100 + j] + Ec[(size_t)lr[1] * 100 + j] +
                Ec[(size_t)lr[2] * 100 + j] + Ec[(size_t)lr[3] * 100 + j];
      m3[x] = e2[x] + 0.25f * s;
    }
    for (int x = tid; x < 100; x += 256)
      sum1[x] = e0[x] + 0.25f * (e1[x] + e1[100 + x] + e1[200 + x] + e1[300 + x]);
    for (int x = tid; x < 400; x += 256) {
      int k = x / 100, j = x % 100;
      const float* e2k = e2 + k * 400;
      sum4[x] = e1[x] + 0.25f * (e2k[j] + e2k[100 + j] + e2k[200 + j] + e2k[300 + j]);
    }
    __syncthreads();
    for (int o = tid; o < 2100; o += 256) {
      const float *in, *W;
      float bia;
      float* dst;
      int i = o % 100;
      if (o < 100)      { in = sum1;                           W = waggT;          bia = baggf[i];       dst = ne0 + o; }
      else if (o < 500) { in = sum4 + ((o - 100) / 100) * 100; W = waggT + 10000;  bia = baggf[100 + i]; dst = ne1 + (o - 100); }
      else              { in = m3 + ((o - 500) / 100) * 100;   W = waggT + 20000;  bia = baggf[200 + i]; dst = ne2 + (o - 500); }
      float acc = bia;
      for (int j = 0; j < 100; j++) acc += in[j] * W[j * 100 + i];
      *dst = tanhf(acc);
    }
    __syncthreads();
    for (int x = tid; x < 100; x += 256)
      sum1[x] = ne0[x] + 0.25f * (ne1[x] + ne1[100 + x] + ne1[200 + x] + ne1[300 + x]);
    for (int x = tid; x < 400; x += 256) {
      int k = x / 100, j = x % 100;
      const float* n2k = ne2 + k * 400;
      sum4[x] = ne1[x] + 0.25f * (n2k[j] + n2k[100 + j] + n2k[200 + j] + n2k[300 + j]);
    }
    __syncthreads();
    for (int o = tid; o < 500; o += 256) {
      int i = o % 100;
      if (o < 100) {
        float acc = baggf[i];
        for (int j = 0; j < 100; j++) acc += sum1[j] * waggT[j * 100 + i];
        e0[i] = tanhf(acc);
      } else {
        const float* in = sum4 + ((o - 100) / 100) * 100;
        float acc = baggf[100 + i];
        for (int j = 0; j < 100; j++) acc += in[j] * waggT[10000 + j * 100 + i];
        e1[o - 100] = tanhf(acc);
      }
    }
    __syncthreads();
    for (int x = tid; x < 100; x += 256)
      sum1[x] = e0[x] + 0.25f * (e1[x] + e1[100 + x] + e1[200 + x] + e1[300 + x]);
    __syncthreads();
    for (int o = tid; o < 100; o += 256) {
      float acc = baggf[o];
      for (int j = 0; j < 100; j++) acc += sum1[j] * waggT[j * 100 + o];
      ne0[o] = tanhf(acc);
    }
    __syncthreads();
    for (int o = tid; o < 100; o += 256) {
      float acc = blastf[o];
      for (int j = 0; j < 100; j++) acc += ne0[j] * wlastT[j * 100 + o];
      emq[o] = tanhf(acc);
    }
    __syncthreads();
  } else {
    for (int x = tid; x < 100; x += 256) emq[x] = Eq[(size_t)qt * 100 + x];
    __syncthreads();
  }

  const size_t bt = (size_t)b * T_ + t;
  for (int o = tid; o < 300; o += 256) {
    float acc = erw[rt * 300 + o];
    for (int j = 0; j < 100; j++) acc += emq[j] * wih1aT[j * 300 + o];
    gi1_all[bt * 300 + o] = acc;
  }
}

// ---------------------------------------------------------------------------
// Phase B (unchanged): qw[5] and top-10 indices per (b,t).
// ---------------------------------------------------------------------------
__global__ __launch_bounds__(128) void phaseB(
    const float* Eq, const float* Ec, const int* question, const int* cidx, const int* cmask,
    const float* wkeyT, const float* b_key, const float* W_W,
    float* qw_all, int* top10_all)
{
  const int t = blockIdx.x, b = blockIdx.y, tid = threadIdx.x;
  const size_t bt = (size_t)b * T_ + t;
  __shared__ float qcf[500];
  __shared__ float qtl[500];
  __shared__ float qwp[20];
  __shared__ float orig[128];
  __shared__ float sval[128];
  __shared__ int sidx[128];
  __shared__ int ci[4], cm[4];

  const int qn = question[b * S_ + t + 1];
  if (tid < 4) { ci[tid] = cidx[qn * KC_ + tid]; cm[tid] = cmask[qn * KC_ + tid]; }
  __syncthreads();

  for (int u = tid; u < 500; u += 128) {
    int row = u / 100, j = u % 100;
    float v;
    if (row == 0) v = Eq[(size_t)qn * 100 + j];
    else {
      int k = row - 1;
      v = cm[k] ? Ec[(size_t)ci[k] * 100 + j] : 0.f;
    }
    qcf[u] = v;
  }
  __syncthreads();
  for (int o = tid; o < 500; o += 128) {
    int q = o / 100, i = o % 100;
    float acc = b_key[i];
    const float* src = qcf + q * 100;
    for (int j = 0; j < 100; j++) acc += src[j] * wkeyT[j * 100 + i];
    qtl[o] = tanhf(acc);
  }
  __syncthreads();
  if (tid < 20) {
    int q = tid / 4, part = tid % 4;
    float acc = 0.f;
    for (int j = part * 25; j < part * 25 + 25; j++) acc += qtl[q * 100 + j] * W_W[j];
    qwp[tid] = acc;
  }
  __syncthreads();
  if (tid < 5) qw_all[bt * 5 + tid] = qwp[tid * 4] + qwp[tid * 4 + 1] + qwp[tid * 4 + 2] + qwp[tid * 4 + 3];

  if (t > RK_) {
    float sc = -__builtin_inff();
    if (tid < t) {
      int qs = question[b * S_ + tid];
      float acc = 0.f;
      for (int j = 0; j < 100; j++) acc += Eq[(size_t)qs * 100 + j] * qcf[j];
      sc = acc;
    }
    orig[tid] = sc;
    __syncthreads();
    for (int pass = 0; pass < 10; pass++) {
      sval[tid] = orig[tid];
      sidx[tid] = tid;
      __syncthreads();
      for (int offt = 64; offt > 0; offt >>= 1) {
        if (tid < offt) {
          float v2 = sval[tid + offt];
          int i2 = sidx[tid + offt];
          if (v2 > sval[tid] || (v2 == sval[tid] && i2 < sidx[tid])) { sval[tid] = v2; sidx[tid] = i2; }
        }
        __syncthreads();
      }
      if (tid == 0) top10_all[bt * 10 + pass] = sidx[0];
      if (tid == sidx[0]) orig[tid] = -__builtin_inff();
      __syncthreads();
    }
  }
}

// fma of 8 bf16-packed weights (one uint4) against 8 floats
__device__ __forceinline__ void fma8(const uint4 w, const float h[8], float& a) {
  a = fmaf(__uint_as_float(w.x << 16),         h[0], a);
  a = fmaf(__uint_as_float(w.x & 0xffff0000u), h[1], a);
  a = fmaf(__uint_as_float(w.y << 16),         h[2], a);
  a = fmaf(__uint_as_float(w.y & 0xffff0000u), h[3], a);
  a = fmaf(__uint_as_float(w.z << 16),         h[4], a);
  a = fmaf(__uint_as_float(w.z & 0xffff0000u), h[5], a);
  a = fmaf(__uint_as_float(w.w << 16),         h[6], a);
  a = fmaf(__uint_as_float(w.w & 0xffff0000u), h[7], a);
}

// ---------------------------------------------------------------------------
// Sequential scan v9: 1024 threads, 3 barriers/step, REGISTER/LDS-RESIDENT
// WEIGHTS. v8 re-read ~256 KB of bf16 weights from L2 every timestep (the
// dominant per-step stall: ~4K cycles of L2 delivery inside the serial
// phases). Now:
//   - W_hh1/W_hh2 triplets + W_query row live in persistent VGPRs. Roles
//     share the SAME named arrays (wS1a/b/c, wQ) so the kernel-wide
//     allocation is 64 VGPRs total, content lane-divergent.
//   - W_ih2 lives in LDS (packed 13 u32 per (row,sub) = 62.4 KB; bank
//     pattern 52g+13s+k mod 32 -> only 2-way (g,g+8) aliasing = free).
// Accumulation order per dot is unchanged (ascending element, zero pads) ->
// numerics bit-identical to v8.
// Phases (unchanged):
//   S1: Whh1 3-dot+GRU1->h1n | Whh2 3-dot->gh2 | og s>=1   -> b1
//   S3: Wih2 3-dot+GRU2->g2v | h1 copy                      -> b2
//   S5: kq | og s=0 | ALL commits + h2/g2hist updates       -> b3
//   S6: wave-0 kw/softmax/store (no trailing barrier; ogs dbuf by parity)
// ---------------------------------------------------------------------------
__global__ __launch_bounds__(1024) void seqk(
    const u32* __restrict__ wcat16, const float* __restrict__ bcat,
    const float* __restrict__ gi1_all, const float* __restrict__ qw_all, const int* __restrict__ top10_all,
    const float* __restrict__ W_W, const float* __restrict__ b_W,
    const float* __restrict__ Eq, const float* __restrict__ Ec, const int* __restrict__ question,
    const int* __restrict__ cidx, const int* __restrict__ cmask,
    const float* __restrict__ h1_init, const float* __restrict__ h2_init, const float* __restrict__ scal,
    float* __restrict__ out)
{
  const int b = blockIdx.x, tid = threadIdx.x;
  const int grp = tid >> 2, sub = tid & 3;  // grp in [0,256)
  const int ptid = tid - 424;               // prefetch lane index
  const uint4* wimg = (const uint4*)wcat16;

  __shared__ float g2hist[T_ * 100];   // 50.8 KB, row 0 = zeros
  __shared__ float hcomb[200];         // h1 | h2
  __shared__ __align__(16) float h1n[100], g2v[100];
  __shared__ float gh2[300], kqs[100];
  __shared__ float gi1d[2][300];
  __shared__ float qcd[2][500];
  __shared__ float qwd[2][5];
  __shared__ int topd[2][10];
  __shared__ float kwhist[128];
  __shared__ float ogs[2][55];
  __shared__ float bresS[1792];
  __shared__ float wkS[100];
  __shared__ int cidS[8], cid0S[8];
  __shared__ int qn1S, qnS;
  __shared__ u32 wih2S[300 * 52];      // 62.4 KB: W_ih2, packed [row][sub(4)][13 u32]

  for (int x = tid; x < 1792; x += 1024) bresS[x] = bcat[x];
  if (tid < 100) wkS[tid] = W_W[100 + tid];

  // one-time: pack W_ih2 image slots [1024,1324) into LDS (13 used u32 of 16)
  for (int x = tid; x < 300 * 52; x += 1024) {
    int s = x / 52, r = x - s * 52;
    int sb = r / 13, k = r - sb * 13;
    wih2S[x] = wcat16[(size_t)(1024 + s) * 64 + sb * 16 + k];
  }

  // one-time: persistent weight registers (role-dependent content, shared names)
  uint4 wS1a[4], wS1b[4], wS1c[4], wQ[4];
  {
    const int s0 = (grp < 100) ? grp : ((grp < 200) ? (300 + grp - 100) : 0);
    const uint4* p0 = wimg + (size_t)s0 * 16 + sub * 4;
    const uint4* p1 = wimg + (size_t)(s0 + 100) * 16 + sub * 4;
    const uint4* p2 = wimg + (size_t)(s0 + 200) * 16 + sub * 4;
    const int sq = (grp < 100) ? (1536 + grp) : 1536;
    const uint4* pq = wimg + (size_t)sq * 16 + sub * 4;
#pragma unroll
    for (int c = 0; c < 4; ++c) { wS1a[c] = p0[c]; wS1b[c] = p1[c]; wS1c[c] = p2[c]; wQ[c] = pq[c]; }
  }

  const float bWv = b_W[0];
  const float kw0 = scal[0];

  if (tid < 100) {
    hcomb[tid] = h1_init[b * 100 + tid];
    g2hist[tid] = 0.f;
  } else if (tid < 200) {
    hcomb[tid] = h2_init[b * 100 + (tid - 100)];
  }
  if (tid < 128) kwhist[tid] = kw0;
  if (tid < 300) gi1d[0][tid] = gi1_all[(size_t)b * T_ * 300 + tid];
  if (tid >= 300 && tid < 305) qwd[0][tid - 300] = qw_all[(size_t)b * T_ * 5 + (tid - 300)];
  if (tid == 306) { qn1S = question[b * S_ + 2]; qnS = question[b * S_ + 3]; }
  if (tid >= 320 && tid < 328) {
    int k = tid - 320, qn0 = question[b * S_ + 1];
    cid0S[k] = (k < 4) ? cidx[qn0 * KC_ + k] : cmask[qn0 * KC_ + k - 4];
  }
  if (tid >= 328 && tid < 336) {
    int k = tid - 328, qn1 = question[b * S_ + 2];
    cidS[k] = (k < 4) ? cidx[qn1 * KC_ + k] : cmask[qn1 * KC_ + k - 4];
  }
  __syncthreads();
  if (tid < 500) {
    int q = tid / 100, j = tid % 100;
    int qn0 = question[b * S_ + 1];
    qcd[0][tid] = (q == 0) ? Eq[(size_t)qn0 * 100 + j]
                           : (cid0S[4 + q - 1] ? Ec[(size_t)cid0S[q - 1] * 100 + j] : 0.f);
  }
  __syncthreads();

  for (int t = 0; t < T_; ++t) {
    const size_t bt = (size_t)b * T_ + t;
    const int cur = t & 1, nxt = cur ^ 1;
    const bool pf = (t + 1) < T_;
    const int qn1 = qn1S, qn2 = qnS;  // stable (committed prior S5, barrier since)

    // ---- TOP: issue ALL t+1 prefetch on tids >= 424 (latency hides under S1) ----
    float pqc = 0.f, pgi = 0.f, pqw = 0.f;
    int ptop = 0, pci = 0, pqn = 0;
    if (pf) {
      if (ptid >= 0 && ptid < 500) {
        int q = ptid / 100, j = ptid % 100;
        pqc = (q == 0) ? Eq[(size_t)qn1 * 100 + j]
                       : (cidS[4 + q - 1] ? Ec[(size_t)cidS[q - 1] * 100 + j] : 0.f);
      }
      if (ptid >= 0 && ptid < 300) pgi = gi1_all[(bt + 1) * 300 + ptid];
      if (tid >= 924 && tid < 929) pqw = qw_all[(bt + 1) * 5 + (tid - 924)];
      if (tid >= 929 && tid < 939 && (t + 1) > RK_) ptop = top10_all[(bt + 1) * 10 + (tid - 929)];
      if (tid >= 939 && tid < 947 && (t + 2) < T_) {
        int k = tid - 939;
        pci = (k < 4) ? cidx[qn2 * KC_ + k] : cmask[qn2 * KC_ + k - 4];
      }
      if (tid == 947) pqn = question[b * S_ + min(t + 4, S_ - 1)];
    }

    // ---- S1: fused gh1+GRU1 (grp<100) | gh2 (grp<200) | og s>=1 (grp<250) ----
    if (grp < 200) {
      const bool g1 = (grp < 100);
      const int j = g1 ? grp : (grp - 100);
      const float* hsrc = hcomb + (g1 ? 0 : 100) + sub * 25;
      float a0 = 0.f, a1 = 0.f, a2 = 0.f;
#pragma unroll
      for (int c = 0; c < 4; ++c) {
        float h[8];
#pragma unroll
        for (int e = 0; e < 8; ++e) h[e] = (c * 8 + e < 25) ? hsrc[c * 8 + e] : 0.f;
        fma8(wS1a[c], h, a0);
        fma8(wS1b[c], h, a1);
        fma8(wS1c[c], h, a2);
      }
      a0 += __shfl_xor(a0, 1); a0 += __shfl_xor(a0, 2);
      a1 += __shfl_xor(a1, 1); a1 += __shfl_xor(a1, 2);
      a2 += __shfl_xor(a2, 1); a2 += __shfl_xor(a2, 2);
      if (sub == 0) {
        if (g1) {
          float g0 = a0 + bresS[j], gg1 = a1 + bresS[100 + j], gg2 = a2 + bresS[200 + j];
          float rg = sigmf(gi1d[cur][j] + g0);
          float z  = sigmf(gi1d[cur][100 + j] + gg1);
          float n  = tanhf(gi1d[cur][200 + j] + rg * gg2);
          h1n[j] = (1.f - z) * n + z * hcomb[j];
        } else {
          gh2[j]       = a0 + bresS[300 + j];
          gh2[100 + j] = a1 + bresS[400 + j];
          gh2[200 + j] = a2 + bresS[500 + j];
        }
      }
    } else if (grp < 250) {
      int d = grp - 200;  // 0..49
      int s = 1 + d / 5, q = d % 5;
      bool valid = (t > RK_) || (s - 1 < t);
      float a = 0.f;
      if (valid) {
        int idx = (t > RK_) ? topd[cur][s - 1] : (s - 1);
        const float* qcr = &qcd[cur][q * 100 + sub * 25];
        const float* hrow = &g2hist[idx * 100 + sub * 25];
#pragma unroll
        for (int c = 0; c < 25; ++c) a = fmaf(qcr[c], hrow[c], a);
      }
      a += __shfl_xor(a, 1);
      a += __shfl_xor(a, 2);
      if (sub == 0) ogs[cur][s * 5 + q] = a;
    }
    __syncthreads();  // b1: h1n, gh2, ogs[cur][5..54] visible

    // ---- S3: fused gi2+GRU2 -> g2v (grp<100, W_ih2 from LDS) | h1 copy ----
    if (grp < 100) {
      const int j = grp;
      const u32* wr0 = wih2S + j * 52 + sub * 13;
      const u32* wr1 = wr0 + 100 * 52;
      const u32* wr2 = wr0 + 200 * 52;
      const float* hsrc = h1n + sub * 25;
      float a0 = 0.f, a1 = 0.f, a2 = 0.f;
#pragma unroll
      for (int k = 0; k < 13; ++k) {
        float h0  = hsrc[2 * k];
        float h1v = (2 * k + 1 < 25) ? hsrc[2 * k + 1] : 0.f;
        u32 w0v = wr0[k], w1v = wr1[k], w2v = wr2[k];
        a0 = fmaf(__uint_as_float(w0v << 16),         h0,  a0);
        a0 = fmaf(__uint_as_float(w0v & 0xffff0000u), h1v, a0);
        a1 = fmaf(__uint_as_float(w1v << 16),         h0,  a1);
        a1 = fmaf(__uint_as_float(w1v & 0xffff0000u), h1v, a1);
        a2 = fmaf(__uint_as_float(w2v << 16),         h0,  a2);
        a2 = fmaf(__uint_as_float(w2v & 0xffff0000u), h1v, a2);
      }
      a0 += __shfl_xor(a0, 1); a0 += __shfl_xor(a0, 2);
      a1 += __shfl_xor(a1, 1); a1 += __shfl_xor(a1, 2);
      a2 += __shfl_xor(a2, 1); a2 += __shfl_xor(a2, 2);
      if (sub == 0) {
        float i_r = a0 + bresS[1024 + j], i_z = a1 + bresS[1124 + j], i_n = a2 + bresS[1224 + j];
        float rg = sigmf(i_r + gh2[j]);
        float z  = sigmf(i_z + gh2[100 + j]);
        float n  = tanhf(i_n + rg * gh2[200 + j]);
        g2v[j] = (1.f - z) * n + z * hcomb[100 + j];
      }
    } else if (tid >= 400 && tid < 500) {
      hcomb[tid - 400] = h1n[tid - 400];  // h1 <- h1n (h1n visible after b1)
    }
    __syncthreads();  // b2: g2v visible

    // ---- S5: kq (grp<100, W_query in regs) | og s=0 (grp<105) | commits (tid>=424) ----
    if (grp < 100) {
      const float* hsrc = g2v + sub * 25;
      float a = 0.f;
#pragma unroll
      for (int c = 0; c < 4; ++c) {
        float h[8];
#pragma unroll
        for (int e = 0; e < 8; ++e) h[e] = (c * 8 + e < 25) ? hsrc[c * 8 + e] : 0.f;
        fma8(wQ[c], h, a);
      }
      a += __shfl_xor(a, 1);
      a += __shfl_xor(a, 2);
      if (sub == 0) kqs[grp] = tanhf(a + bresS[1536 + grp]) * wkS[grp];
    } else if (grp < 105) {
      int q = grp - 100;
      const float* qcr = &qcd[cur][q * 100 + sub * 25];
      float a = 0.f;
#pragma unroll
      for (int c = 0; c < 25; ++c) a = fmaf(qcr[c], g2v[sub * 25 + c], a);
      a += __shfl_xor(a, 1);
      a += __shfl_xor(a, 2);
      if (sub == 0) ogs[cur][q] = a;
    }
    if (ptid >= 0) {
      if (pf) {
        if (ptid < 500) qcd[nxt][ptid] = pqc;
        if (ptid < 300) gi1d[nxt][ptid] = pgi;
        if (tid >= 924 && tid < 929) qwd[nxt][tid - 924] = pqw;
        if (tid >= 929 && tid < 939 && (t + 1) > RK_) topd[nxt][tid - 929] = min(T_ - 1, max(0, ptop));
        if (tid >= 939 && tid < 947 && (t + 2) < T_) cidS[tid - 939] = pci;
        if (tid == 947) { qn1S = qn2; qnS = pqn; }
      }
      if (t > 0 && ptid < 100) {
        hcomb[100 + ptid] = g2v[ptid];
        g2hist[t * 100 + ptid] = g2v[ptid];
      }
    }
    __syncthreads();  // b3: kqs, ogs, commits, state updates visible

    // ---- S6: wave-0 kw reduce + softmax + store (no trailing barrier) ----
    if (tid < 64) {
      float v = (tid < 50) ? (kqs[tid] + kqs[tid + 50]) : 0.f;
      v += __shfl_xor(v, 1);
      v += __shfl_xor(v, 2);
      v += __shfl_xor(v, 4);
      v += __shfl_xor(v, 8);
      v += __shfl_xor(v, 16);
      v += __shfl_xor(v, 32);
      const float kw = v;  // all 64 lanes
      float pq = 0.f;
      if (tid < 5) {
        const float qw = qwd[cur][tid];
        float tmp[11];
        float m = -__builtin_inff();
#pragma unroll
        for (int s = 0; s < 11; ++s) {
          float kws;
          bool valid;
          if (s == 0) { kws = kw; valid = true; }
          else if (t > RK_) { kws = kwhist[topd[cur][s - 1]]; valid = true; }
          else { valid = (s - 1 < t); kws = kwhist[s - 1]; }
          float tv = valid ? (qw + kws + bWv) : NEGV;
          tmp[s] = tv;
          m = fmaxf(m, tv);
        }
        float den = 0.f, num = 0.f;
#pragma unroll
        for (int s = 0; s < 11; ++s) {
          float e = expf(tmp[s] - m);
          den += e;
          num += e * ogs[cur][s * 5 + tid];
        }
        pq = num / den;
      }
      if (tid == 5 && t > 0) kwhist[t] = kw;  // read only by wave 0 (program order)
      float sp = pq;
      sp += __shfl_xor(sp, 1);
      sp += __shfl_xor(sp, 2);
      sp += __shfl_xor(sp, 4);
      if (tid == 0) {
        int col = (t == 0) ? 0 : (t + 1);
        out[b * S_ + col] = sp;
        if (t == 0) out[b * S_ + 1] = 0.f;  // col 1 never written by ref
      }
    }
    // no barrier: next step's S1 writes (h1n/gh2/ogs[nxt]) are race-free vs S6
    // (ogs parity-dbuf; kqs/qwd/topd[cur]/kwhist only touched by wave 0 or
    //  behind next step's b2 which requires wave 0 to pass b1 first)
  }
}

// ---------------------------------------------------------------------------
extern "C" void kernel_launch(void* const* d_in, const int* in_sizes, int n_in,
                              void* d_out, int out_size, void* d_ws, size_t ws_size,
                              hipStream_t stream)
{
  (void)in_sizes; (void)n_in; (void)out_size; (void)ws_size;
  const float* Eq     = (const float*)d_in[0];
  const float* Ec     = (const float*)d_in[1];
  const float* Er     = (const float*)d_in[2];
  const float* W_ih1  = (const float*)d_in[3];
  const float* W_hh1  = (const float*)d_in[4];
  const float* b_ih1  = (const float*)d_in[5];
  const float* b_hh1  = (const float*)d_in[6];
  const float* W_ih2  = (const float*)d_in[7];
  const float* W_hh2  = (const float*)d_in[8];
  const float* b_ih2  = (const float*)d_in[9];
  const float* b_hh2  = (const float*)d_in[10];
  const float* Wagg   = (const float*)d_in[11];
  const float* bagg   = (const float*)d_in[12];
  const float* W_last = (const float*)d_in[13];
  const float* b_last = (const float*)d_in[14];
  const float* W_query= (const float*)d_in[15];
  const float* b_query= (const float*)d_in[16];
  const float* W_key  = (const float*)d_in[17];
  const float* b_key  = (const float*)d_in[18];
  const float* W_W    = (const float*)d_in[19];
  const float* b_W    = (const float*)d_in[20];
  const float* h1_init= (const float*)d_in[21];
  const float* h2_init= (const float*)d_in[22];
  const int* question = (const int*)d_in[23];
  const int* response = (const int*)d_in[24];
  const int* mask     = (const int*)d_in[25];
  const int* qnb      = (const int*)d_in[26];
  const int* snb      = (const int*)d_in[27];
  const int* cidx     = (const int*)d_in[28];
  const int* cmask    = (const int*)d_in[29];
  float* out = (float*)d_out;

  char* ws = (char*)d_ws;
  size_t off = 0;
  auto alloc = [&](size_t bytes) -> void* {
    void* p = ws + off;
    off += (bytes + 255) & ~(size_t)255;
    return p;
  };
  float* wih1aT = (float*)alloc(30000 * 4);
  float* erw    = (float*)alloc(600 * 4);
  float* waggT  = (float*)alloc(30000 * 4);
  float* wlastT = (float*)alloc(10000 * 4);
  float* wkeyT  = (float*)alloc(10000 * 4);
  float* scal   = (float*)alloc(4);
  u32*   wcat16 = (u32*)alloc(114688 * 4);
  float* bcat   = (float*)alloc(1792 * 4);
  float* gi1_all = (float*)alloc((size_t)B_ * T_ * 300 * 4);
  float* qw_all  = (float*)alloc((size_t)B_ * T_ * 5 * 4);
  int*   top10   = (int*)alloc((size_t)B_ * T_ * 10 * 4);

  hipLaunchKernelGGL(setupk, dim3(128), dim3(256), 0, stream,
      Er, W_ih1, b_ih1, Wagg, W_last, W_key, b_query, W_W, W_query,
      W_hh1, W_hh2, W_ih2, b_hh1, b_hh2, b_ih2,
      wih1aT, erw, waggT, wlastT, wkeyT, scal, wcat16, bcat);

  hipLaunchKernelGGL(phaseA, dim3(T_, B_), dim3(256), 0, stream,
      Eq, Ec, question, response, mask, qnb, snb,
      wih1aT, erw, waggT, wlastT, bagg, b_last, gi1_all);

  hipLaunchKernelGGL(phaseB, dim3(T_, B_), dim3(128), 0, stream,
      Eq, Ec, question, cidx, cmask, wkeyT, b_key, W_W,
      qw_all, top10);

  hipLaunchKernelGGL(seqk, dim3(B_), dim3(1024), 0, stream,
      wcat16, bcat, gi1_all, qw_all, top10, W_W, b_W,
      Eq, Ec, question, cidx, cmask,
      h1_init, h2_init, scal, out);
}

// Round 2
// 1773.928 us; speedup vs baseline: 1.3161x; 1.3161x over previous
//
#include <hip/hip_runtime.h>
#include <hip/hip_bf16.h>
#include <math.h>

typedef unsigned int u32;

#define B_ 128
#define S_ 128
#define T_ 127
#define D_ 100
#define QN_ 4
#define SN_ 4
#define KC_ 4
#define RK_ 10
#define NEGV -1000000000.0f

__device__ __forceinline__ float sigmf(float x) { return 1.0f / (1.0f + expf(-x)); }

__device__ __forceinline__ u32 f2bfbits(float x) {
  __hip_bfloat16 h = __float2bfloat16(x);
  unsigned short s;
  __builtin_memcpy(&s, &h, 2);
  return (u32)s;
}

// ---------------------------------------------------------------------------
// Setup (unchanged): transposed f32 weights for phaseA/B; erw fold;
// kw0 scalar; bf16 lane-swizzled weight image (1792 slots x 64 u32 = 256B):
//   [0,300): W_hh1 | [300,600): W_hh2 | [1024,1324): W_ih2 | [1536,1636): W_query
// slot bytes: [sub(4)][k(16 u32)], u32 k packs bf16 cols (sub*25+2k, +2k+1).
// ---------------------------------------------------------------------------
__global__ __launch_bounds__(256) void setupk(
    const float* Er, const float* W_ih1, const float* b_ih1,
    const float* Wagg, const float* W_last, const float* W_key,
    const float* b_query, const float* W_W, const float* W_query,
    const float* W_hh1, const float* W_hh2, const float* W_ih2,
    const float* b_hh1, const float* b_hh2, const float* b_ih2,
    float* wih1aT, float* erw, float* waggT, float* wlastT, float* wkeyT,
    float* scal, u32* wcat16, float* bcat)
{
  int gid = blockIdx.x * blockDim.x + threadIdx.x;
  int gsz = gridDim.x * blockDim.x;

  for (int x = gid; x < 30000; x += gsz) {
    int j = x / 300, i = x % 300;
    wih1aT[j * 300 + i] = W_ih1[i * 200 + j];
  }
  for (int x = gid; x < 600; x += gsz) {
    int r = x / 300, i = x % 300;
    float acc = b_ih1[i];
    for (int j = 0; j < 100; j++) acc += Er[r * 100 + j] * W_ih1[i * 200 + 100 + j];
    erw[x] = acc;
  }
  for (int x = gid; x < 30000; x += gsz) {
    int h = x / 10000, rr = x % 10000, j = rr / 100, i = rr % 100;
    waggT[h * 10000 + j * 100 + i] = Wagg[h * 10000 + i * 100 + j];
  }
  for (int x = gid; x < 10000; x += gsz) {
    int j = x / 100, i = x % 100;
    wlastT[j * 100 + i] = W_last[i * 100 + j];
    wkeyT[j * 100 + i] = W_key[i * 100 + j];
  }
  for (int x = gid; x < 114688; x += gsz) {
    int slot = x / 64, rem = x % 64, sbu = rem / 16, k = rem % 16;
    const float* src = nullptr;
    if (slot < 300)                       src = W_hh1 + (size_t)slot * 100;
    else if (slot < 600)                  src = W_hh2 + (size_t)(slot - 300) * 100;
    else if (slot >= 1024 && slot < 1324) src = W_ih2 + (size_t)(slot - 1024) * 100;
    else if (slot >= 1536 && slot < 1636) src = W_query + (size_t)(slot - 1536) * 100;
    u32 lo = 0, hi = 0;
    if (src) {
      int e0 = 2 * k, e1 = 2 * k + 1;
      if (e0 < 25) lo = f2bfbits(src[sbu * 25 + e0]);
      if (e1 < 25) hi = f2bfbits(src[sbu * 25 + e1]);
    }
    wcat16[x] = (hi << 16) | lo;
  }
  for (int x = gid; x < 1792; x += gsz) {
    float v = 0.f;
    if (x < 300) v = b_hh1[x];
    else if (x < 600) v = b_hh2[x - 300];
    else if (x >= 1024 && x < 1324) v = b_ih2[x - 1024];
    else if (x >= 1536 && x < 1636) v = b_query[x - 1536];
    bcat[x] = v;
  }
  if (gid == 0) {
    float acc = 0.f;  // kw of the all-zero hist state: dot(tanh(b_query), Wk_part)
    for (int i = 0; i < 100; i++) acc += tanhf(b_query[i]) * W_W[100 + i];
    scal[0] = acc;
  }
}

// ---------------------------------------------------------------------------
// Phase A (unchanged): per (b,t) 3-hop aggregate -> gi1[b,t,0:300]
// ---------------------------------------------------------------------------
__global__ __launch_bounds__(256) void phaseA(
    const float* Eq, const float* Ec, const int* question, const int* response, const int* mask,
    const int* qnb, const int* snb,
    const float* wih1aT, const float* erw, const float* waggT, const float* wlastT,
    const float* baggf, const float* blastf, float* gi1_all)
{
  const int t = blockIdx.x, b = blockIdx.y, tid = threadIdx.x;
  __shared__ float e0[100], ne0[100], e1[400], ne1[400];
  __shared__ float e2[1600], ne2[1600], m3[1600];
  __shared__ float sum4[400], sum1[100], emq[100];
  __shared__ int l1[4], l2[16], l3[64];

  const int qt = question[b * S_ + t];
  const int mt = mask[b * S_ + t];
  const int rt = response[b * S_ + t];

  if (mt != 0) {
    if (tid < 4) l1[tid] = qnb[qt * QN_ + tid];
    for (int x = tid; x < 100; x += 256) e0[x] = Eq[(size_t)qt * 100 + x];
    __syncthreads();
    if (tid < 16) l2[tid] = snb[l1[tid >> 2] * SN_ + (tid & 3)];
    for (int x = tid; x < 400; x += 256) e1[x] = Ec[(size_t)l1[x / 100] * 100 + (x % 100)];
    __syncthreads();
    if (tid < 64) l3[tid] = qnb[l2[tid >> 2] * QN_ + (tid & 3)];
    for (int x = tid; x < 1600; x += 256) e2[x] = Eq[(size_t)l2[x / 100] * 100 + (x % 100)];
    __syncthreads();
    for (int x = tid; x < 1600; x += 256) {
      int r = x / 100, j = x % 100;
      const int* lr = l3 + r * 4;
      float s = Ec[(size_t)lr[0] * 100 + j] + Ec[(size_t)lr[1] * 100 + j] +
                Ec[(size_t)lr[2] * 100 + j] + Ec[(size_t)lr[3] * 100 + j];
      m3[x] = e2[x] + 0.25f * s;
    }
    for (int x = tid; x < 100; x += 256)
      sum1[x] = e0[x] + 0.25f * (e1[x] + e1[100 + x] + e1[200 + x] + e1[300 + x]);
    for (int x = tid; x < 400; x += 256) {
      int k = x / 100, j = x % 100;
      const float* e2k = e2 + k * 400;
      sum4[x] = e1[x] + 0.25f * (e2k[j] + e2k[100 + j] + e2k[200 + j] + e2k[300 + j]);
    }
    __syncthreads();
    for (int o = tid; o < 2100; o += 256) {
      const float *in, *W;
      float bia;
      float* dst;
      int i = o % 100;
      if (o < 100)      { in = sum1;                           W = waggT;          bia = baggf[i];       dst = ne0 + o; }
      else if (o < 500) { in = sum4 + ((o - 100) / 100) * 100; W = waggT + 10000;  bia = baggf[100 + i]; dst = ne1 + (o - 100); }
      else              { in = m3 + ((o - 500) / 100) * 100;   W = waggT + 20000;  bia = baggf[200 + i]; dst = ne2 + (o - 500); }
      float acc = bia;
      for (int j = 0; j < 100; j++) acc += in[j] * W[j * 100 + i];
      *dst = tanhf(acc);
    }
    __syncthreads();
    for (int x = tid; x < 100; x += 256)
      sum1[x] = ne0[x] + 0.25f * (ne1[x] + ne1[100 + x] + ne1[200 + x] + ne1[300 + x]);
    for (int x = tid; x < 400; x += 256) {
      int k = x / 100, j = x % 100;
      const float* n2k = ne2 + k * 400;
      sum4[x] = ne1[x] + 0.25f * (n2k[j] + n2k[100 + j] + n2k[200 + j] + n2k[300 + j]);
    }
    __syncthreads();
    for (int o = tid; o < 500; o += 256) {
      int i = o % 100;
      if (o < 100) {
        float acc = baggf[i];
        for (int j = 0; j < 100; j++) acc += sum1[j] * waggT[j * 100 + i];
        e0[i] = tanhf(acc);
      } else {
        const float* in = sum4 + ((o - 100) / 100) * 100;
        float acc = baggf[100 + i];
        for (int j = 0; j < 100; j++) acc += in[j] * waggT[10000 + j * 100 + i];
        e1[o - 100] = tanhf(acc);
      }
    }
    __syncthreads();
    for (int x = tid; x < 100; x += 256)
      sum1[x] = e0[x] + 0.25f * (e1[x] + e1[100 + x] + e1[200 + x] + e1[300 + x]);
    __syncthreads();
    for (int o = tid; o < 100; o += 256) {
      float acc = baggf[o];
      for (int j = 0; j < 100; j++) acc += sum1[j] * waggT[j * 100 + o];
      ne0[o] = tanhf(acc);
    }
    __syncthreads();
    for (int o = tid; o < 100; o += 256) {
      float acc = blastf[o];
      for (int j = 0; j < 100; j++) acc += ne0[j] * wlastT[j * 100 + o];
      emq[o] = tanhf(acc);
    }
    __syncthreads();
  } else {
    for (int x = tid; x < 100; x += 256) emq[x] = Eq[(size_t)qt * 100 + x];
    __syncthreads();
  }

  const size_t bt = (size_t)b * T_ + t;
  for (int o = tid; o < 300; o += 256) {
    float acc = erw[rt * 300 + o];
    for (int j = 0; j < 100; j++) acc += emq[j] * wih1aT[j * 300 + o];
    gi1_all[bt * 300 + o] = acc;
  }
}

// ---------------------------------------------------------------------------
// Phase B (unchanged): qw[5] and top-10 indices per (b,t).
// ---------------------------------------------------------------------------
__global__ __launch_bounds__(128) void phaseB(
    const float* Eq, const float* Ec, const int* question, const int* cidx, const int* cmask,
    const float* wkeyT, const float* b_key, const float* W_W,
    float* qw_all, int* top10_all)
{
  const int t = blockIdx.x, b = blockIdx.y, tid = threadIdx.x;
  const size_t bt = (size_t)b * T_ + t;
  __shared__ float qcf[500];
  __shared__ float qtl[500];
  __shared__ float qwp[20];
  __shared__ float orig[128];
  __shared__ float sval[128];
  __shared__ int sidx[128];
  __shared__ int ci[4], cm[4];

  const int qn = question[b * S_ + t + 1];
  if (tid < 4) { ci[tid] = cidx[qn * KC_ + tid]; cm[tid] = cmask[qn * KC_ + tid]; }
  __syncthreads();

  for (int u = tid; u < 500; u += 128) {
    int row = u / 100, j = u % 100;
    float v;
    if (row == 0) v = Eq[(size_t)qn * 100 + j];
    else {
      int k = row - 1;
      v = cm[k] ? Ec[(size_t)ci[k] * 100 + j] : 0.f;
    }
    qcf[u] = v;
  }
  __syncthreads();
  for (int o = tid; o < 500; o += 128) {
    int q = o / 100, i = o % 100;
    float acc = b_key[i];
    const float* src = qcf + q * 100;
    for (int j = 0; j < 100; j++) acc += src[j] * wkeyT[j * 100 + i];
    qtl[o] = tanhf(acc);
  }
  __syncthreads();
  if (tid < 20) {
    int q = tid / 4, part = tid % 4;
    float acc = 0.f;
    for (int j = part * 25; j < part * 25 + 25; j++) acc += qtl[q * 100 + j] * W_W[j];
    qwp[tid] = acc;
  }
  __syncthreads();
  if (tid < 5) qw_all[bt * 5 + tid] = qwp[tid * 4] + qwp[tid * 4 + 1] + qwp[tid * 4 + 2] + qwp[tid * 4 + 3];

  if (t > RK_) {
    float sc = -__builtin_inff();
    if (tid < t) {
      int qs = question[b * S_ + tid];
      float acc = 0.f;
      for (int j = 0; j < 100; j++) acc += Eq[(size_t)qs * 100 + j] * qcf[j];
      sc = acc;
    }
    orig[tid] = sc;
    __syncthreads();
    for (int pass = 0; pass < 10; pass++) {
      sval[tid] = orig[tid];
      sidx[tid] = tid;
      __syncthreads();
      for (int offt = 64; offt > 0; offt >>= 1) {
        if (tid < offt) {
          float v2 = sval[tid + offt];
          int i2 = sidx[tid + offt];
          if (v2 > sval[tid] || (v2 == sval[tid] && i2 < sidx[tid])) { sval[tid] = v2; sidx[tid] = i2; }
        }
        __syncthreads();
      }
      if (tid == 0) top10_all[bt * 10 + pass] = sidx[0];
      if (tid == sidx[0]) orig[tid] = -__builtin_inff();
      __syncthreads();
    }
  }
}

// fma of 8 bf16-packed weights (one uint4) against 8 floats
__device__ __forceinline__ void fma8(const uint4 w, const float h[8], float& a) {
  a = fmaf(__uint_as_float(w.x << 16),         h[0], a);
  a = fmaf(__uint_as_float(w.x & 0xffff0000u), h[1], a);
  a = fmaf(__uint_as_float(w.y << 16),         h[2], a);
  a = fmaf(__uint_as_float(w.y & 0xffff0000u), h[3], a);
  a = fmaf(__uint_as_float(w.z << 16),         h[4], a);
  a = fmaf(__uint_as_float(w.z & 0xffff0000u), h[5], a);
  a = fmaf(__uint_as_float(w.w << 16),         h[6], a);
  a = fmaf(__uint_as_float(w.w & 0xffff0000u), h[7], a);
}

// ---------------------------------------------------------------------------
// Sequential scan v10: 1024 threads, 3 barriers/step, weight-resident.
// v9 failed because the compiler kept a 64-VGPR occupancy target (2 blk/CU)
// and spilled the persistent weight arrays to scratch (WRITE_SIZE 11.8->123MB,
// VGPR_Count stayed 64). Fixes:
//   - __launch_bounds__(1024, 4): exactly 1 block/CU (what we launch anyway),
//     VGPR cap 128 -> persistent weights stay in registers.
//   - Persistent register demand cut to 48 VGPRs: only the S1 W_hh1/W_hh2
//     triplets (wS1a/b/c, 12 uint4, lane-divergent content, shared names).
//   - W_ih2 AND W_query in LDS (13 used u32 per (row,sub): 62.4 + 20.8 KB).
//     Bank pattern 52g+13s+k mod 32 -> only (g,g+8) 2-way alias = free.
// Accumulation order per dot unchanged (ascending element, exact-zero pads)
// -> numerics bit-identical to v8.
// Phases (unchanged):
//   S1: Whh1 3-dot+GRU1->h1n | Whh2 3-dot->gh2 | og s>=1   -> b1
//   S3: Wih2 3-dot+GRU2->g2v | h1 copy                      -> b2
//   S5: kq | og s=0 | ALL commits + h2/g2hist updates       -> b3
//   S6: wave-0 kw/softmax/store (no trailing barrier; ogs dbuf by parity)
// ---------------------------------------------------------------------------
__global__ __launch_bounds__(1024, 4) void seqk(
    const u32* __restrict__ wcat16, const float* __restrict__ bcat,
    const float* __restrict__ gi1_all, const float* __restrict__ qw_all, const int* __restrict__ top10_all,
    const float* __restrict__ W_W, const float* __restrict__ b_W,
    const float* __restrict__ Eq, const float* __restrict__ Ec, const int* __restrict__ question,
    const int* __restrict__ cidx, const int* __restrict__ cmask,
    const float* __restrict__ h1_init, const float* __restrict__ h2_init, const float* __restrict__ scal,
    float* __restrict__ out)
{
  const int b = blockIdx.x, tid = threadIdx.x;
  const int grp = tid >> 2, sub = tid & 3;  // grp in [0,256)
  const int ptid = tid - 424;               // prefetch lane index
  const uint4* wimg = (const uint4*)wcat16;

  __shared__ float g2hist[T_ * 100];   // 50.8 KB, row 0 = zeros
  __shared__ float hcomb[200];         // h1 | h2
  __shared__ __align__(16) float h1n[100], g2v[100];
  __shared__ float gh2[300], kqs[100];
  __shared__ float gi1d[2][300];
  __shared__ float qcd[2][500];
  __shared__ float qwd[2][5];
  __shared__ int topd[2][10];
  __shared__ float kwhist[128];
  __shared__ float ogs[2][55];
  __shared__ float bresS[1792];
  __shared__ float wkS[100];
  __shared__ int cidS[8], cid0S[8];
  __shared__ int qn1S, qnS;
  __shared__ u32 wih2S[300 * 52];      // 62.4 KB: W_ih2,   packed [row][sub(4)][13 u32]
  __shared__ u32 wqS[100 * 52];        // 20.8 KB: W_query, packed [row][sub(4)][13 u32]

  for (int x = tid; x < 1792; x += 1024) bresS[x] = bcat[x];
  if (tid < 100) wkS[tid] = W_W[100 + tid];

  // one-time: pack W_ih2 slots [1024,1324) and W_query slots [1536,1636) into LDS
  for (int x = tid; x < 300 * 52; x += 1024) {
    int s = x / 52, r = x - s * 52;
    int sb = r / 13, k = r - sb * 13;
    wih2S[x] = wcat16[(size_t)(1024 + s) * 64 + sb * 16 + k];
  }
  for (int x = tid; x < 100 * 52; x += 1024) {
    int s = x / 52, r = x - s * 52;
    int sb = r / 13, k = r - sb * 13;
    wqS[x] = wcat16[(size_t)(1536 + s) * 64 + sb * 16 + k];
  }

  // one-time: persistent S1 weight registers (role-dependent content, shared names)
  uint4 wS1a[4], wS1b[4], wS1c[4];
  {
    const int s0 = (grp < 100) ? grp : ((grp < 200) ? (300 + grp - 100) : 0);
    const uint4* p0 = wimg + (size_t)s0 * 16 + sub * 4;
    const uint4* p1 = wimg + (size_t)(s0 + 100) * 16 + sub * 4;
    const uint4* p2 = wimg + (size_t)(s0 + 200) * 16 + sub * 4;
#pragma unroll
    for (int c = 0; c < 4; ++c) { wS1a[c] = p0[c]; wS1b[c] = p1[c]; wS1c[c] = p2[c]; }
  }

  const float bWv = b_W[0];
  const float kw0 = scal[0];

  if (tid < 100) {
    hcomb[tid] = h1_init[b * 100 + tid];
    g2hist[tid] = 0.f;
  } else if (tid < 200) {
    hcomb[tid] = h2_init[b * 100 + (tid - 100)];
  }
  if (tid < 128) kwhist[tid] = kw0;
  if (tid < 300) gi1d[0][tid] = gi1_all[(size_t)b * T_ * 300 + tid];
  if (tid >= 300 && tid < 305) qwd[0][tid - 300] = qw_all[(size_t)b * T_ * 5 + (tid - 300)];
  if (tid == 306) { qn1S = question[b * S_ + 2]; qnS = question[b * S_ + 3]; }
  if (tid >= 320 && tid < 328) {
    int k = tid - 320, qn0 = question[b * S_ + 1];
    cid0S[k] = (k < 4) ? cidx[qn0 * KC_ + k] : cmask[qn0 * KC_ + k - 4];
  }
  if (tid >= 328 && tid < 336) {
    int k = tid - 328, qn1 = question[b * S_ + 2];
    cidS[k] = (k < 4) ? cidx[qn1 * KC_ + k] : cmask[qn1 * KC_ + k - 4];
  }
  __syncthreads();
  if (tid < 500) {
    int q = tid / 100, j = tid % 100;
    int qn0 = question[b * S_ + 1];
    qcd[0][tid] = (q == 0) ? Eq[(size_t)qn0 * 100 + j]
                           : (cid0S[4 + q - 1] ? Ec[(size_t)cid0S[q - 1] * 100 + j] : 0.f);
  }
  __syncthreads();

  for (int t = 0; t < T_; ++t) {
    const size_t bt = (size_t)b * T_ + t;
    const int cur = t & 1, nxt = cur ^ 1;
    const bool pf = (t + 1) < T_;
    const int qn1 = qn1S, qn2 = qnS;  // stable (committed prior S5, barrier since)

    // ---- TOP: issue ALL t+1 prefetch on tids >= 424 (latency hides under S1) ----
    float pqc = 0.f, pgi = 0.f, pqw = 0.f;
    int ptop = 0, pci = 0, pqn = 0;
    if (pf) {
      if (ptid >= 0 && ptid < 500) {
        int q = ptid / 100, j = ptid % 100;
        pqc = (q == 0) ? Eq[(size_t)qn1 * 100 + j]
                       : (cidS[4 + q - 1] ? Ec[(size_t)cidS[q - 1] * 100 + j] : 0.f);
      }
      if (ptid >= 0 && ptid < 300) pgi = gi1_all[(bt + 1) * 300 + ptid];
      if (tid >= 924 && tid < 929) pqw = qw_all[(bt + 1) * 5 + (tid - 924)];
      if (tid >= 929 && tid < 939 && (t + 1) > RK_) ptop = top10_all[(bt + 1) * 10 + (tid - 929)];
      if (tid >= 939 && tid < 947 && (t + 2) < T_) {
        int k = tid - 939;
        pci = (k < 4) ? cidx[qn2 * KC_ + k] : cmask[qn2 * KC_ + k - 4];
      }
      if (tid == 947) pqn = question[b * S_ + min(t + 4, S_ - 1)];
    }

    // ---- S1: fused gh1+GRU1 (grp<100) | gh2 (grp<200) | og s>=1 (grp<250) ----
    if (grp < 200) {
      const bool g1 = (grp < 100);
      const int j = g1 ? grp : (grp - 100);
      const float* hsrc = hcomb + (g1 ? 0 : 100) + sub * 25;
      float a0 = 0.f, a1 = 0.f, a2 = 0.f;
#pragma unroll
      for (int c = 0; c < 4; ++c) {
        float h[8];
#pragma unroll
        for (int e = 0; e < 8; ++e) h[e] = (c * 8 + e < 25) ? hsrc[c * 8 + e] : 0.f;
        fma8(wS1a[c], h, a0);
        fma8(wS1b[c], h, a1);
        fma8(wS1c[c], h, a2);
      }
      a0 += __shfl_xor(a0, 1); a0 += __shfl_xor(a0, 2);
      a1 += __shfl_xor(a1, 1); a1 += __shfl_xor(a1, 2);
      a2 += __shfl_xor(a2, 1); a2 += __shfl_xor(a2, 2);
      if (sub == 0) {
        if (g1) {
          float g0 = a0 + bresS[j], gg1 = a1 + bresS[100 + j], gg2 = a2 + bresS[200 + j];
          float rg = sigmf(gi1d[cur][j] + g0);
          float z  = sigmf(gi1d[cur][100 + j] + gg1);
          float n  = tanhf(gi1d[cur][200 + j] + rg * gg2);
          h1n[j] = (1.f - z) * n + z * hcomb[j];
        } else {
          gh2[j]       = a0 + bresS[300 + j];
          gh2[100 + j] = a1 + bresS[400 + j];
          gh2[200 + j] = a2 + bresS[500 + j];
        }
      }
    } else if (grp < 250) {
      int d = grp - 200;  // 0..49
      int s = 1 + d / 5, q = d % 5;
      bool valid = (t > RK_) || (s - 1 < t);
      float a = 0.f;
      if (valid) {
        int idx = (t > RK_) ? topd[cur][s - 1] : (s - 1);
        const float* qcr = &qcd[cur][q * 100 + sub * 25];
        const float* hrow = &g2hist[idx * 100 + sub * 25];
#pragma unroll
        for (int c = 0; c < 25; ++c) a = fmaf(qcr[c], hrow[c], a);
      }
      a += __shfl_xor(a, 1);
      a += __shfl_xor(a, 2);
      if (sub == 0) ogs[cur][s * 5 + q] = a;
    }
    __syncthreads();  // b1: h1n, gh2, ogs[cur][5..54] visible

    // ---- S3: fused gi2+GRU2 -> g2v (grp<100, W_ih2 from LDS) | h1 copy ----
    if (grp < 100) {
      const int j = grp;
      const u32* wr0 = wih2S + j * 52 + sub * 13;
      const u32* wr1 = wr0 + 100 * 52;
      const u32* wr2 = wr0 + 200 * 52;
      const float* hsrc = h1n + sub * 25;
      float a0 = 0.f, a1 = 0.f, a2 = 0.f;
#pragma unroll
      for (int k = 0; k < 13; ++k) {
        float h0  = hsrc[2 * k];
        float h1v = (2 * k + 1 < 25) ? hsrc[2 * k + 1] : 0.f;
        u32 w0v = wr0[k], w1v = wr1[k], w2v = wr2[k];
        a0 = fmaf(__uint_as_float(w0v << 16),         h0,  a0);
        a0 = fmaf(__uint_as_float(w0v & 0xffff0000u), h1v, a0);
        a1 = fmaf(__uint_as_float(w1v << 16),         h0,  a1);
        a1 = fmaf(__uint_as_float(w1v & 0xffff0000u), h1v, a1);
        a2 = fmaf(__uint_as_float(w2v << 16),         h0,  a2);
        a2 = fmaf(__uint_as_float(w2v & 0xffff0000u), h1v, a2);
      }
      a0 += __shfl_xor(a0, 1); a0 += __shfl_xor(a0, 2);
      a1 += __shfl_xor(a1, 1); a1 += __shfl_xor(a1, 2);
      a2 += __shfl_xor(a2, 1); a2 += __shfl_xor(a2, 2);
      if (sub == 0) {
        float i_r = a0 + bresS[1024 + j], i_z = a1 + bresS[1124 + j], i_n = a2 + bresS[1224 + j];
        float rg = sigmf(i_r + gh2[j]);
        float z  = sigmf(i_z + gh2[100 + j]);
        float n  = tanhf(i_n + rg * gh2[200 + j]);
        g2v[j] = (1.f - z) * n + z * hcomb[100 + j];
      }
    } else if (tid >= 400 && tid < 500) {
      hcomb[tid - 400] = h1n[tid - 400];  // h1 <- h1n (h1n visible after b1)
    }
    __syncthreads();  // b2: g2v visible

    // ---- S5: kq (grp<100, W_query from LDS) | og s=0 (grp<105) | commits (tid>=424) ----
    if (grp < 100) {
      const u32* wq = wqS + grp * 52 + sub * 13;
      const float* hsrc = g2v + sub * 25;
      float a = 0.f;
#pragma unroll
      for (int k = 0; k < 13; ++k) {
        float h0  = hsrc[2 * k];
        float h1v = (2 * k + 1 < 25) ? hsrc[2 * k + 1] : 0.f;
        u32 wv = wq[k];
        a = fmaf(__uint_as_float(wv << 16),         h0,  a);
        a = fmaf(__uint_as_float(wv & 0xffff0000u), h1v, a);
      }
      a += __shfl_xor(a, 1);
      a += __shfl_xor(a, 2);
      if (sub == 0) kqs[grp] = tanhf(a + bresS[1536 + grp]) * wkS[grp];
    } else if (grp < 105) {
      int q = grp - 100;
      const float* qcr = &qcd[cur][q * 100 + sub * 25];
      float a = 0.f;
#pragma unroll
      for (int c = 0; c < 25; ++c) a = fmaf(qcr[c], g2v[sub * 25 + c], a);
      a += __shfl_xor(a, 1);
      a += __shfl_xor(a, 2);
      if (sub == 0) ogs[cur][q] = a;
    }
    if (ptid >= 0) {
      if (pf) {
        if (ptid < 500) qcd[nxt][ptid] = pqc;
        if (ptid < 300) gi1d[nxt][ptid] = pgi;
        if (tid >= 924 && tid < 929) qwd[nxt][tid - 924] = pqw;
        if (tid >= 929 && tid < 939 && (t + 1) > RK_) topd[nxt][tid - 929] = min(T_ - 1, max(0, ptop));
        if (tid >= 939 && tid < 947 && (t + 2) < T_) cidS[tid - 939] = pci;
        if (tid == 947) { qn1S = qn2; qnS = pqn; }
      }
      if (t > 0 && ptid < 100) {
        hcomb[100 + ptid] = g2v[ptid];
        g2hist[t * 100 + ptid] = g2v[ptid];
      }
    }
    __syncthreads();  // b3: kqs, ogs, commits, state updates visible

    // ---- S6: wave-0 kw reduce + softmax + store (no trailing barrier) ----
    if (tid < 64) {
      float v = (tid < 50) ? (kqs[tid] + kqs[tid + 50]) : 0.f;
      v += __shfl_xor(v, 1);
      v += __shfl_xor(v, 2);
      v += __shfl_xor(v, 4);
      v += __shfl_xor(v, 8);
      v += __shfl_xor(v, 16);
      v += __shfl_xor(v, 32);
      const float kw = v;  // all 64 lanes
      float pq = 0.f;
      if (tid < 5) {
        const float qw = qwd[cur][tid];
        float tmp[11];
        float m = -__builtin_inff();
#pragma unroll
        for (int s = 0; s < 11; ++s) {
          float kws;
          bool valid;
          if (s == 0) { kws = kw; valid = true; }
          else if (t > RK_) { kws = kwhist[topd[cur][s - 1]]; valid = true; }
          else { valid = (s - 1 < t); kws = kwhist[s - 1]; }
          float tv = valid ? (qw + kws + bWv) : NEGV;
          tmp[s] = tv;
          m = fmaxf(m, tv);
        }
        float den = 0.f, num = 0.f;
#pragma unroll
        for (int s = 0; s < 11; ++s) {
          float e = expf(tmp[s] - m);
          den += e;
          num += e * ogs[cur][s * 5 + tid];
        }
        pq = num / den;
      }
      if (tid == 5 && t > 0) kwhist[t] = kw;  // read only by wave 0 (program order)
      float sp = pq;
      sp += __shfl_xor(sp, 1);
      sp += __shfl_xor(sp, 2);
      sp += __shfl_xor(sp, 4);
      if (tid == 0) {
        int col = (t == 0) ? 0 : (t + 1);
        out[b * S_ + col] = sp;
        if (t == 0) out[b * S_ + 1] = 0.f;  // col 1 never written by ref
      }
    }
    // no barrier: next step's S1 writes (h1n/gh2/ogs[nxt]) are race-free vs S6
    // (ogs parity-dbuf; kqs/qwd/topd[cur]/kwhist only touched by wave 0 or
    //  behind next step's b2 which requires wave 0 to pass b1 first)
  }
}

// ---------------------------------------------------------------------------
extern "C" void kernel_launch(void* const* d_in, const int* in_sizes, int n_in,
                              void* d_out, int out_size, void* d_ws, size_t ws_size,
                              hipStream_t stream)
{
  (void)in_sizes; (void)n_in; (void)out_size; (void)ws_size;
  const float* Eq     = (const float*)d_in[0];
  const float* Ec     = (const float*)d_in[1];
  const float* Er     = (const float*)d_in[2];
  const float* W_ih1  = (const float*)d_in[3];
  const float* W_hh1  = (const float*)d_in[4];
  const float* b_ih1  = (const float*)d_in[5];
  const float* b_hh1  = (const float*)d_in[6];
  const float* W_ih2  = (const float*)d_in[7];
  const float* W_hh2  = (const float*)d_in[8];
  const float* b_ih2  = (const float*)d_in[9];
  const float* b_hh2  = (const float*)d_in[10];
  const float* Wagg   = (const float*)d_in[11];
  const float* bagg   = (const float*)d_in[12];
  const float* W_last = (const float*)d_in[13];
  const float* b_last = (const float*)d_in[14];
  const float* W_query= (const float*)d_in[15];
  const float* b_query= (const float*)d_in[16];
  const float* W_key  = (const float*)d_in[17];
  const float* b_key  = (const float*)d_in[18];
  const float* W_W    = (const float*)d_in[19];
  const float* b_W    = (const float*)d_in[20];
  const float* h1_init= (const float*)d_in[21];
  const float* h2_init= (const float*)d_in[22];
  const int* question = (const int*)d_in[23];
  const int* response = (const int*)d_in[24];
  const int* mask     = (const int*)d_in[25];
  const int* qnb      = (const int*)d_in[26];
  const int* snb      = (const int*)d_in[27];
  const int* cidx     = (const int*)d_in[28];
  const int* cmask    = (const int*)d_in[29];
  float* out = (float*)d_out;

  char* ws = (char*)d_ws;
  size_t off = 0;
  auto alloc = [&](size_t bytes) -> void* {
    void* p = ws + off;
    off += (bytes + 255) & ~(size_t)255;
    return p;
  };
  float* wih1aT = (float*)alloc(30000 * 4);
  float* erw    = (float*)alloc(600 * 4);
  float* waggT  = (float*)alloc(30000 * 4);
  float* wlastT = (float*)alloc(10000 * 4);
  float* wkeyT  = (float*)alloc(10000 * 4);
  float* scal   = (float*)alloc(4);
  u32*   wcat16 = (u32*)alloc(114688 * 4);
  float* bcat   = (float*)alloc(1792 * 4);
  float* gi1_all = (float*)alloc((size_t)B_ * T_ * 300 * 4);
  float* qw_all  = (float*)alloc((size_t)B_ * T_ * 5 * 4);
  int*   top10   = (int*)alloc((size_t)B_ * T_ * 10 * 4);

  hipLaunchKernelGGL(setupk, dim3(128), dim3(256), 0, stream,
      Er, W_ih1, b_ih1, Wagg, W_last, W_key, b_query, W_W, W_query,
      W_hh1, W_hh2, W_ih2, b_hh1, b_hh2, b_ih2,
      wih1aT, erw, waggT, wlastT, wkeyT, scal, wcat16, bcat);

  hipLaunchKernelGGL(phaseA, dim3(T_, B_), dim3(256), 0, stream,
      Eq, Ec, question, response, mask, qnb, snb,
      wih1aT, erw, waggT, wlastT, bagg, b_last, gi1_all);

  hipLaunchKernelGGL(phaseB, dim3(T_, B_), dim3(128), 0, stream,
      Eq, Ec, question, cidx, cmask, wkeyT, b_key, W_W,
      qw_all, top10);

  hipLaunchKernelGGL(seqk, dim3(B_), dim3(1024), 0, stream,
      wcat16, bcat, gi1_all, qw_all, top10, W_W, b_W,
      Eq, Ec, question, cidx, cmask,
      h1_init, h2_init, scal, out);
}

// Round 3
// 1498.805 us; speedup vs baseline: 1.5577x; 1.1836x over previous
//
#include <hip/hip_runtime.h>
#include <hip/hip_bf16.h>
#include <math.h>

typedef unsigned int u32;

#define B_ 128
#define S_ 128
#define T_ 127
#define D_ 100
#define QN_ 4
#define SN_ 4
#define KC_ 4
#define RK_ 10
#define NEGV -1000000000.0f

__device__ __forceinline__ float sigmf(float x) { return 1.0f / (1.0f + expf(-x)); }

__device__ __forceinline__ u32 f2bfbits(float x) {
  __hip_bfloat16 h = __float2bfloat16(x);
  unsigned short s;
  __builtin_memcpy(&s, &h, 2);
  return (u32)s;
}

// ---------------------------------------------------------------------------
// Setup (unchanged): transposed f32 weights for phaseA/B; erw fold;
// kw0 scalar; bf16 lane-swizzled weight image (1792 slots x 64 u32 = 256B):
//   [0,300): W_hh1 | [300,600): W_hh2 | [1024,1324): W_ih2 | [1536,1636): W_query
// slot bytes: [sub(4)][k(16 u32)], u32 k packs bf16 cols (sub*25+2k, +2k+1).
// ---------------------------------------------------------------------------
__global__ __launch_bounds__(256) void setupk(
    const float* Er, const float* W_ih1, const float* b_ih1,
    const float* Wagg, const float* W_last, const float* W_key,
    const float* b_query, const float* W_W, const float* W_query,
    const float* W_hh1, const float* W_hh2, const float* W_ih2,
    const float* b_hh1, const float* b_hh2, const float* b_ih2,
    float* wih1aT, float* erw, float* waggT, float* wlastT, float* wkeyT,
    float* scal, u32* wcat16, float* bcat)
{
  int gid = blockIdx.x * blockDim.x + threadIdx.x;
  int gsz = gridDim.x * blockDim.x;

  for (int x = gid; x < 30000; x += gsz) {
    int j = x / 300, i = x % 300;
    wih1aT[j * 300 + i] = W_ih1[i * 200 + j];
  }
  for (int x = gid; x < 600; x += gsz) {
    int r = x / 300, i = x % 300;
    float acc = b_ih1[i];
    for (int j = 0; j < 100; j++) acc += Er[r * 100 + j] * W_ih1[i * 200 + 100 + j];
    erw[x] = acc;
  }
  for (int x = gid; x < 30000; x += gsz) {
    int h = x / 10000, rr = x % 10000, j = rr / 100, i = rr % 100;
    waggT[h * 10000 + j * 100 + i] = Wagg[h * 10000 + i * 100 + j];
  }
  for (int x = gid; x < 10000; x += gsz) {
    int j = x / 100, i = x % 100;
    wlastT[j * 100 + i] = W_last[i * 100 + j];
    wkeyT[j * 100 + i] = W_key[i * 100 + j];
  }
  for (int x = gid; x < 114688; x += gsz) {
    int slot = x / 64, rem = x % 64, sbu = rem / 16, k = rem % 16;
    const float* src = nullptr;
    if (slot < 300)                       src = W_hh1 + (size_t)slot * 100;
    else if (slot < 600)                  src = W_hh2 + (size_t)(slot - 300) * 100;
    else if (slot >= 1024 && slot < 1324) src = W_ih2 + (size_t)(slot - 1024) * 100;
    else if (slot >= 1536 && slot < 1636) src = W_query + (size_t)(slot - 1536) * 100;
    u32 lo = 0, hi = 0;
    if (src) {
      int e0 = 2 * k, e1 = 2 * k + 1;
      if (e0 < 25) lo = f2bfbits(src[sbu * 25 + e0]);
      if (e1 < 25) hi = f2bfbits(src[sbu * 25 + e1]);
    }
    wcat16[x] = (hi << 16) | lo;
  }
  for (int x = gid; x < 1792; x += gsz) {
    float v = 0.f;
    if (x < 300) v = b_hh1[x];
    else if (x < 600) v = b_hh2[x - 300];
    else if (x >= 1024 && x < 1324) v = b_ih2[x - 1024];
    else if (x >= 1536 && x < 1636) v = b_query[x - 1536];
    bcat[x] = v;
  }
  if (gid == 0) {
    float acc = 0.f;  // kw of the all-zero hist state: dot(tanh(b_query), Wk_part)
    for (int i = 0; i < 100; i++) acc += tanhf(b_query[i]) * W_W[100 + i];
    scal[0] = acc;
  }
}

// ---------------------------------------------------------------------------
// Phase A (unchanged): per (b,t) 3-hop aggregate -> gi1[b,t,0:300]
// ---------------------------------------------------------------------------
__global__ __launch_bounds__(256) void phaseA(
    const float* Eq, const float* Ec, const int* question, const int* response, const int* mask,
    const int* qnb, const int* snb,
    const float* wih1aT, const float* erw, const float* waggT, const float* wlastT,
    const float* baggf, const float* blastf, float* gi1_all)
{
  const int t = blockIdx.x, b = blockIdx.y, tid = threadIdx.x;
  __shared__ float e0[100], ne0[100], e1[400], ne1[400];
  __shared__ float e2[1600], ne2[1600], m3[1600];
  __shared__ float sum4[400], sum1[100], emq[100];
  __shared__ int l1[4], l2[16], l3[64];

  const int qt = question[b * S_ + t];
  const int mt = mask[b * S_ + t];
  const int rt = response[b * S_ + t];

  if (mt != 0) {
    if (tid < 4) l1[tid] = qnb[qt * QN_ + tid];
    for (int x = tid; x < 100; x += 256) e0[x] = Eq[(size_t)qt * 100 + x];
    __syncthreads();
    if (tid < 16) l2[tid] = snb[l1[tid >> 2] * SN_ + (tid & 3)];
    for (int x = tid; x < 400; x += 256) e1[x] = Ec[(size_t)l1[x / 100] * 100 + (x % 100)];
    __syncthreads();
    if (tid < 64) l3[tid] = qnb[l2[tid >> 2] * QN_ + (tid & 3)];
    for (int x = tid; x < 1600; x += 256) e2[x] = Eq[(size_t)l2[x / 100] * 100 + (x % 100)];
    __syncthreads();
    for (int x = tid; x < 1600; x += 256) {
      int r = x / 100, j = x % 100;
      const int* lr = l3 + r * 4;
      float s = Ec[(size_t)lr[0] * 100 + j] + Ec[(size_t)lr[1] * 100 + j] +
                Ec[(size_t)lr[2] * 100 + j] + Ec[(size_t)lr[3] * 100 + j];
      m3[x] = e2[x] + 0.25f * s;
    }
    for (int x = tid; x < 100; x += 256)
      sum1[x] = e0[x] + 0.25f * (e1[x] + e1[100 + x] + e1[200 + x] + e1[300 + x]);
    for (int x = tid; x < 400; x += 256) {
      int k = x / 100, j = x % 100;
      const float* e2k = e2 + k * 400;
      sum4[x] = e1[x] + 0.25f * (e2k[j] + e2k[100 + j] + e2k[200 + j] + e2k[300 + j]);
    }
    __syncthreads();
    for (int o = tid; o < 2100; o += 256) {
      const float *in, *W;
      float bia;
      float* dst;
      int i = o % 100;
      if (o < 100)      { in = sum1;                           W = waggT;          bia = baggf[i];       dst = ne0 + o; }
      else if (o < 500) { in = sum4 + ((o - 100) / 100) * 100; W = waggT + 10000;  bia = baggf[100 + i]; dst = ne1 + (o - 100); }
      else              { in = m3 + ((o - 500) / 100) * 100;   W = waggT + 20000;  bia = baggf[200 + i]; dst = ne2 + (o - 500); }
      float acc = bia;
      for (int j = 0; j < 100; j++) acc += in[j] * W[j * 100 + i];
      *dst = tanhf(acc);
    }
    __syncthreads();
    for (int x = tid; x < 100; x += 256)
      sum1[x] = ne0[x] + 0.25f * (ne1[x] + ne1[100 + x] + ne1[200 + x] + ne1[300 + x]);
    for (int x = tid; x < 400; x += 256) {
      int k = x / 100, j = x % 100;
      const float* n2k = ne2 + k * 400;
      sum4[x] = ne1[x] + 0.25f * (n2k[j] + n2k[100 + j] + n2k[200 + j] + n2k[300 + j]);
    }
    __syncthreads();
    for (int o = tid; o < 500; o += 256) {
      int i = o % 100;
      if (o < 100) {
        float acc = baggf[i];
        for (int j = 0; j < 100; j++) acc += sum1[j] * waggT[j * 100 + i];
        e0[i] = tanhf(acc);
      } else {
        const float* in = sum4 + ((o - 100) / 100) * 100;
        float acc = baggf[100 + i];
        for (int j = 0; j < 100; j++) acc += in[j] * waggT[10000 + j * 100 + i];
        e1[o - 100] = tanhf(acc);
      }
    }
    __syncthreads();
    for (int x = tid; x < 100; x += 256)
      sum1[x] = e0[x] + 0.25f * (e1[x] + e1[100 + x] + e1[200 + x] + e1[300 + x]);
    __syncthreads();
    for (int o = tid; o < 100; o += 256) {
      float acc = baggf[o];
      for (int j = 0; j < 100; j++) acc += sum1[j] * waggT[j * 100 + o];
      ne0[o] = tanhf(acc);
    }
    __syncthreads();
    for (int o = tid; o < 100; o += 256) {
      float acc = blastf[o];
      for (int j = 0; j < 100; j++) acc += ne0[j] * wlastT[j * 100 + o];
      emq[o] = tanhf(acc);
    }
    __syncthreads();
  } else {
    for (int x = tid; x < 100; x += 256) emq[x] = Eq[(size_t)qt * 100 + x];
    __syncthreads();
  }

  const size_t bt = (size_t)b * T_ + t;
  for (int o = tid; o < 300; o += 256) {
    float acc = erw[rt * 300 + o];
    for (int j = 0; j < 100; j++) acc += emq[j] * wih1aT[j * 300 + o];
    gi1_all[bt * 300 + o] = acc;
  }
}

// ---------------------------------------------------------------------------
// Phase B (unchanged): qw[5] and top-10 indices per (b,t).
// ---------------------------------------------------------------------------
__global__ __launch_bounds__(128) void phaseB(
    const float* Eq, const float* Ec, const int* question, const int* cidx, const int* cmask,
    const float* wkeyT, const float* b_key, const float* W_W,
    float* qw_all, int* top10_all)
{
  const int t = blockIdx.x, b = blockIdx.y, tid = threadIdx.x;
  const size_t bt = (size_t)b * T_ + t;
  __shared__ float qcf[500];
  __shared__ float qtl[500];
  __shared__ float qwp[20];
  __shared__ float orig[128];
  __shared__ float sval[128];
  __shared__ int sidx[128];
  __shared__ int ci[4], cm[4];

  const int qn = question[b * S_ + t + 1];
  if (tid < 4) { ci[tid] = cidx[qn * KC_ + tid]; cm[tid] = cmask[qn * KC_ + tid]; }
  __syncthreads();

  for (int u = tid; u < 500; u += 128) {
    int row = u / 100, j = u % 100;
    float v;
    if (row == 0) v = Eq[(size_t)qn * 100 + j];
    else {
      int k = row - 1;
      v = cm[k] ? Ec[(size_t)ci[k] * 100 + j] : 0.f;
    }
    qcf[u] = v;
  }
  __syncthreads();
  for (int o = tid; o < 500; o += 128) {
    int q = o / 100, i = o % 100;
    float acc = b_key[i];
    const float* src = qcf + q * 100;
    for (int j = 0; j < 100; j++) acc += src[j] * wkeyT[j * 100 + i];
    qtl[o] = tanhf(acc);
  }
  __syncthreads();
  if (tid < 20) {
    int q = tid / 4, part = tid % 4;
    float acc = 0.f;
    for (int j = part * 25; j < part * 25 + 25; j++) acc += qtl[q * 100 + j] * W_W[j];
    qwp[tid] = acc;
  }
  __syncthreads();
  if (tid < 5) qw_all[bt * 5 + tid] = qwp[tid * 4] + qwp[tid * 4 + 1] + qwp[tid * 4 + 2] + qwp[tid * 4 + 3];

  if (t > RK_) {
    float sc = -__builtin_inff();
    if (tid < t) {
      int qs = question[b * S_ + tid];
      float acc = 0.f;
      for (int j = 0; j < 100; j++) acc += Eq[(size_t)qs * 100 + j] * qcf[j];
      sc = acc;
    }
    orig[tid] = sc;
    __syncthreads();
    for (int pass = 0; pass < 10; pass++) {
      sval[tid] = orig[tid];
      sidx[tid] = tid;
      __syncthreads();
      for (int offt = 64; offt > 0; offt >>= 1) {
        if (tid < offt) {
          float v2 = sval[tid + offt];
          int i2 = sidx[tid + offt];
          if (v2 > sval[tid] || (v2 == sval[tid] && i2 < sidx[tid])) { sval[tid] = v2; sidx[tid] = i2; }
        }
        __syncthreads();
      }
      if (tid == 0) top10_all[bt * 10 + pass] = sidx[0];
      if (tid == sidx[0]) orig[tid] = -__builtin_inff();
      __syncthreads();
    }
  }
}

// bf16 row-dot helper: dot(unpack(w[0..3]), hr[0..31])
__device__ __forceinline__ float bf16_dot32(const uint4 w[4], const float hr[32]) {
  float a = 0.f;
#pragma unroll
  for (int c = 0; c < 4; ++c) {
    uint4 ww = w[c];
    const int e = c * 8;
    a = fmaf(__uint_as_float(ww.x << 16),         hr[e + 0], a);
    a = fmaf(__uint_as_float(ww.x & 0xffff0000u), hr[e + 1], a);
    a = fmaf(__uint_as_float(ww.y << 16),         hr[e + 2], a);
    a = fmaf(__uint_as_float(ww.y & 0xffff0000u), hr[e + 3], a);
    a = fmaf(__uint_as_float(ww.z << 16),         hr[e + 4], a);
    a = fmaf(__uint_as_float(ww.z & 0xffff0000u), hr[e + 5], a);
    a = fmaf(__uint_as_float(ww.w << 16),         hr[e + 6], a);
    a = fmaf(__uint_as_float(ww.w & 0xffff0000u), hr[e + 7], a);
  }
  return a;
}

// ---------------------------------------------------------------------------
// Sequential scan v11 (hybrid): 1024 threads, 3 barriers/step.
// A/B decomposition of v9/v10's failures:
//   - S1 weights "persistent in VGPRs" NEVER materialized: allocator stayed
//     at 64 VGPRs and spilled to scratch (WRITE_SIZE 11.8->27.9/122MB) both
//     with and without __launch_bounds__(.,4). Scratch round-trip is WORSE
//     than v8's direct L2 streaming. -> REVERT S1 to exact v8 streaming.
//   - S3/S5 weights in LDS (wih2S/wqS, 83.2 KB, 2-way bank alias = free)
//     were the winning component (R1 1650 -> R2 1065). -> KEEP.
// Phases (identical structure to v8):
//   S1: Whh1 3-dot+GRU1->h1n | Whh2 3-dot->gh2 | og s>=1   -> b1
//   S3: Wih2 3-dot+GRU2->g2v (LDS weights) | h1 copy        -> b2
//   S5: kq (LDS weights) | og s=0 | commits + h2/g2hist     -> b3
//   S6: wave-0 kw/softmax/store (no trailing barrier; ogs dbuf by parity)
// ---------------------------------------------------------------------------
__global__ __launch_bounds__(1024) void seqk(
    const u32* __restrict__ wcat16, const float* __restrict__ bcat,
    const float* __restrict__ gi1_all, const float* __restrict__ qw_all, const int* __restrict__ top10_all,
    const float* __restrict__ W_W, const float* __restrict__ b_W,
    const float* __restrict__ Eq, const float* __restrict__ Ec, const int* __restrict__ question,
    const int* __restrict__ cidx, const int* __restrict__ cmask,
    const float* __restrict__ h1_init, const float* __restrict__ h2_init, const float* __restrict__ scal,
    float* __restrict__ out)
{
  const int b = blockIdx.x, tid = threadIdx.x;
  const int grp = tid >> 2, sub = tid & 3;  // grp in [0,256)
  const int ptid = tid - 424;               // prefetch lane index
  const uint4* wimg = (const uint4*)wcat16;

  __shared__ float g2hist[T_ * 100];   // 50.8 KB, row 0 = zeros
  __shared__ float hcomb[200];         // h1 | h2
  __shared__ __align__(16) float h1n[100], g2v[100];
  __shared__ float gh2[300], kqs[100];
  __shared__ float gi1d[2][300];
  __shared__ float qcd[2][500];
  __shared__ float qwd[2][5];
  __shared__ int topd[2][10];
  __shared__ float kwhist[128];
  __shared__ float ogs[2][55];
  __shared__ float bresS[1792];
  __shared__ float wkS[100];
  __shared__ int cidS[8], cid0S[8];
  __shared__ int qn1S, qnS;
  __shared__ u32 wih2S[300 * 52];      // 62.4 KB: W_ih2,   packed [row][sub(4)][13 u32]
  __shared__ u32 wqS[100 * 52];        // 20.8 KB: W_query, packed [row][sub(4)][13 u32]

  for (int x = tid; x < 1792; x += 1024) bresS[x] = bcat[x];
  if (tid < 100) wkS[tid] = W_W[100 + tid];

  // one-time: pack W_ih2 slots [1024,1324) and W_query slots [1536,1636) into LDS
  for (int x = tid; x < 300 * 52; x += 1024) {
    int s = x / 52, r = x - s * 52;
    int sb = r / 13, k = r - sb * 13;
    wih2S[x] = wcat16[(size_t)(1024 + s) * 64 + sb * 16 + k];
  }
  for (int x = tid; x < 100 * 52; x += 1024) {
    int s = x / 52, r = x - s * 52;
    int sb = r / 13, k = r - sb * 13;
    wqS[x] = wcat16[(size_t)(1536 + s) * 64 + sb * 16 + k];
  }

  const float bWv = b_W[0];
  const float kw0 = scal[0];

  if (tid < 100) {
    hcomb[tid] = h1_init[b * 100 + tid];
    g2hist[tid] = 0.f;
  } else if (tid < 200) {
    hcomb[tid] = h2_init[b * 100 + (tid - 100)];
  }
  if (tid < 128) kwhist[tid] = kw0;
  if (tid < 300) gi1d[0][tid] = gi1_all[(size_t)b * T_ * 300 + tid];
  if (tid >= 300 && tid < 305) qwd[0][tid - 300] = qw_all[(size_t)b * T_ * 5 + (tid - 300)];
  if (tid == 306) { qn1S = question[b * S_ + 2]; qnS = question[b * S_ + 3]; }
  if (tid >= 320 && tid < 328) {
    int k = tid - 320, qn0 = question[b * S_ + 1];
    cid0S[k] = (k < 4) ? cidx[qn0 * KC_ + k] : cmask[qn0 * KC_ + k - 4];
  }
  if (tid >= 328 && tid < 336) {
    int k = tid - 328, qn1 = question[b * S_ + 2];
    cidS[k] = (k < 4) ? cidx[qn1 * KC_ + k] : cmask[qn1 * KC_ + k - 4];
  }
  __syncthreads();
  if (tid < 500) {
    int q = tid / 100, j = tid % 100;
    int qn0 = question[b * S_ + 1];
    qcd[0][tid] = (q == 0) ? Eq[(size_t)qn0 * 100 + j]
                           : (cid0S[4 + q - 1] ? Ec[(size_t)cid0S[q - 1] * 100 + j] : 0.f);
  }
  __syncthreads();

  for (int t = 0; t < T_; ++t) {
    const size_t bt = (size_t)b * T_ + t;
    const int cur = t & 1, nxt = cur ^ 1;
    const bool pf = (t + 1) < T_;
    const int qn1 = qn1S, qn2 = qnS;  // stable (committed prior S5, barrier since)

    // ---- TOP: issue ALL t+1 prefetch on tids >= 424 (latency hides under S1) ----
    float pqc = 0.f, pgi = 0.f, pqw = 0.f;
    int ptop = 0, pci = 0, pqn = 0;
    if (pf) {
      if (ptid >= 0 && ptid < 500) {
        int q = ptid / 100, j = ptid % 100;
        pqc = (q == 0) ? Eq[(size_t)qn1 * 100 + j]
                       : (cidS[4 + q - 1] ? Ec[(size_t)cidS[q - 1] * 100 + j] : 0.f);
      }
      if (ptid >= 0 && ptid < 300) pgi = gi1_all[(bt + 1) * 300 + ptid];
      if (tid >= 924 && tid < 929) pqw = qw_all[(bt + 1) * 5 + (tid - 924)];
      if (tid >= 929 && tid < 939 && (t + 1) > RK_) ptop = top10_all[(bt + 1) * 10 + (tid - 929)];
      if (tid >= 939 && tid < 947 && (t + 2) < T_) {
        int k = tid - 939;
        pci = (k < 4) ? cidx[qn2 * KC_ + k] : cmask[qn2 * KC_ + k - 4];
      }
      if (tid == 947) pqn = question[b * S_ + min(t + 4, S_ - 1)];
    }

    // ---- S1: fused gh1+GRU1 (grp<100) | gh2 (grp<200) | og s>=1 (grp<250) ----
    if (grp < 200) {
      const bool g1 = (grp < 100);
      const int j = g1 ? grp : (grp - 100);
      const int s0 = g1 ? j : (300 + j);
      uint4 w0[4], w1[4], w2[4];
      {
        const uint4* p0 = wimg + (size_t)s0 * 16 + sub * 4;
        const uint4* p1 = wimg + (size_t)(s0 + 100) * 16 + sub * 4;
        const uint4* p2 = wimg + (size_t)(s0 + 200) * 16 + sub * 4;
#pragma unroll
        for (int c = 0; c < 4; ++c) { w0[c] = p0[c]; w1[c] = p1[c]; w2[c] = p2[c]; }
      }
      float hr[32];
#pragma unroll
      for (int c = 25; c < 32; ++c) hr[c] = 0.f;
      const int off = g1 ? 0 : 100;
#pragma unroll
      for (int c = 0; c < 25; ++c) hr[c] = hcomb[off + sub * 25 + c];
      float a0 = bf16_dot32(w0, hr);
      float a1 = bf16_dot32(w1, hr);
      float a2 = bf16_dot32(w2, hr);
      a0 += __shfl_xor(a0, 1); a0 += __shfl_xor(a0, 2);
      a1 += __shfl_xor(a1, 1); a1 += __shfl_xor(a1, 2);
      a2 += __shfl_xor(a2, 1); a2 += __shfl_xor(a2, 2);
      if (sub == 0) {
        if (g1) {
          float g0 = a0 + bresS[j], gg1 = a1 + bresS[100 + j], gg2 = a2 + bresS[200 + j];
          float rg = sigmf(gi1d[cur][j] + g0);
          float z  = sigmf(gi1d[cur][100 + j] + gg1);
          float n  = tanhf(gi1d[cur][200 + j] + rg * gg2);
          h1n[j] = (1.f - z) * n + z * hcomb[j];
        } else {
          gh2[j]       = a0 + bresS[300 + j];
          gh2[100 + j] = a1 + bresS[400 + j];
          gh2[200 + j] = a2 + bresS[500 + j];
        }
      }
    } else if (grp < 250) {
      int d = grp - 200;  // 0..49
      int s = 1 + d / 5, q = d % 5;
      bool valid = (t > RK_) || (s - 1 < t);
      float a = 0.f;
      if (valid) {
        int idx = (t > RK_) ? topd[cur][s - 1] : (s - 1);
        const float* qcr = &qcd[cur][q * 100 + sub * 25];
        const float* hrow = &g2hist[idx * 100 + sub * 25];
#pragma unroll
        for (int c = 0; c < 25; ++c) a = fmaf(qcr[c], hrow[c], a);
      }
      a += __shfl_xor(a, 1);
      a += __shfl_xor(a, 2);
      if (sub == 0) ogs[cur][s * 5 + q] = a;
    }
    __syncthreads();  // b1: h1n, gh2, ogs[cur][5..54] visible

    // ---- S3: fused gi2+GRU2 -> g2v (grp<100, W_ih2 from LDS) | h1 copy ----
    if (grp < 100) {
      const int j = grp;
      const u32* wr0 = wih2S + j * 52 + sub * 13;
      const u32* wr1 = wr0 + 100 * 52;
      const u32* wr2 = wr0 + 200 * 52;
      const float* hsrc = h1n + sub * 25;
      float a0 = 0.f, a1 = 0.f, a2 = 0.f;
#pragma unroll
      for (int k = 0; k < 13; ++k) {
        float h0  = hsrc[2 * k];
        float h1v = (2 * k + 1 < 25) ? hsrc[2 * k + 1] : 0.f;
        u32 w0v = wr0[k], w1v = wr1[k], w2v = wr2[k];
        a0 = fmaf(__uint_as_float(w0v << 16),         h0,  a0);
        a0 = fmaf(__uint_as_float(w0v & 0xffff0000u), h1v, a0);
        a1 = fmaf(__uint_as_float(w1v << 16),         h0,  a1);
        a1 = fmaf(__uint_as_float(w1v & 0xffff0000u), h1v, a1);
        a2 = fmaf(__uint_as_float(w2v << 16),         h0,  a2);
        a2 = fmaf(__uint_as_float(w2v & 0xffff0000u), h1v, a2);
      }
      a0 += __shfl_xor(a0, 1); a0 += __shfl_xor(a0, 2);
      a1 += __shfl_xor(a1, 1); a1 += __shfl_xor(a1, 2);
      a2 += __shfl_xor(a2, 1); a2 += __shfl_xor(a2, 2);
      if (sub == 0) {
        float i_r = a0 + bresS[1024 + j], i_z = a1 + bresS[1124 + j], i_n = a2 + bresS[1224 + j];
        float rg = sigmf(i_r + gh2[j]);
        float z  = sigmf(i_z + gh2[100 + j]);
        float n  = tanhf(i_n + rg * gh2[200 + j]);
        g2v[j] = (1.f - z) * n + z * hcomb[100 + j];
      }
    } else if (tid >= 400 && tid < 500) {
      hcomb[tid - 400] = h1n[tid - 400];  // h1 <- h1n (h1n visible after b1)
    }
    __syncthreads();  // b2: g2v visible

    // ---- S5: kq (grp<100, W_query from LDS) | og s=0 (grp<105) | commits (tid>=424) ----
    if (grp < 100) {
      const u32* wq = wqS + grp * 52 + sub * 13;
      const float* hsrc = g2v + sub * 25;
      float a = 0.f;
#pragma unroll
      for (int k = 0; k < 13; ++k) {
        float h0  = hsrc[2 * k];
        float h1v = (2 * k + 1 < 25) ? hsrc[2 * k + 1] : 0.f;
        u32 wv = wq[k];
        a = fmaf(__uint_as_float(wv << 16),         h0,  a);
        a = fmaf(__uint_as_float(wv & 0xffff0000u), h1v, a);
      }
      a += __shfl_xor(a, 1);
      a += __shfl_xor(a, 2);
      if (sub == 0) kqs[grp] = tanhf(a + bresS[1536 + grp]) * wkS[grp];
    } else if (grp < 105) {
      int q = grp - 100;
      const float* qcr = &qcd[cur][q * 100 + sub * 25];
      float a = 0.f;
#pragma unroll
      for (int c = 0; c < 25; ++c) a = fmaf(qcr[c], g2v[sub * 25 + c], a);
      a += __shfl_xor(a, 1);
      a += __shfl_xor(a, 2);
      if (sub == 0) ogs[cur][q] = a;
    }
    if (ptid >= 0) {
      if (pf) {
        if (ptid < 500) qcd[nxt][ptid] = pqc;
        if (ptid < 300) gi1d[nxt][ptid] = pgi;
        if (tid >= 924 && tid < 929) qwd[nxt][tid - 924] = pqw;
        if (tid >= 929 && tid < 939 && (t + 1) > RK_) topd[nxt][tid - 929] = min(T_ - 1, max(0, ptop));
        if (tid >= 939 && tid < 947 && (t + 2) < T_) cidS[tid - 939] = pci;
        if (tid == 947) { qn1S = qn2; qnS = pqn; }
      }
      if (t > 0 && ptid < 100) {
        hcomb[100 + ptid] = g2v[ptid];
        g2hist[t * 100 + ptid] = g2v[ptid];
      }
    }
    __syncthreads();  // b3: kqs, ogs, commits, state updates visible

    // ---- S6: wave-0 kw reduce + softmax + store (no trailing barrier) ----
    if (tid < 64) {
      float v = (tid < 50) ? (kqs[tid] + kqs[tid + 50]) : 0.f;
      v += __shfl_xor(v, 1);
      v += __shfl_xor(v, 2);
      v += __shfl_xor(v, 4);
      v += __shfl_xor(v, 8);
      v += __shfl_xor(v, 16);
      v += __shfl_xor(v, 32);
      const float kw = v;  // all 64 lanes
      float pq = 0.f;
      if (tid < 5) {
        const float qw = qwd[cur][tid];
        float tmp[11];
        float m = -__builtin_inff();
#pragma unroll
        for (int s = 0; s < 11; ++s) {
          float kws;
          bool valid;
          if (s == 0) { kws = kw; valid = true; }
          else if (t > RK_) { kws = kwhist[topd[cur][s - 1]]; valid = true; }
          else { valid = (s - 1 < t); kws = kwhist[s - 1]; }
          float tv = valid ? (qw + kws + bWv) : NEGV;
          tmp[s] = tv;
          m = fmaxf(m, tv);
        }
        float den = 0.f, num = 0.f;
#pragma unroll
        for (int s = 0; s < 11; ++s) {
          float e = expf(tmp[s] - m);
          den += e;
          num += e * ogs[cur][s * 5 + tid];
        }
        pq = num / den;
      }
      if (tid == 5 && t > 0) kwhist[t] = kw;  // read only by wave 0 (program order)
      float sp = pq;
      sp += __shfl_xor(sp, 1);
      sp += __shfl_xor(sp, 2);
      sp += __shfl_xor(sp, 4);
      if (tid == 0) {
        int col = (t == 0) ? 0 : (t + 1);
        out[b * S_ + col] = sp;
        if (t == 0) out[b * S_ + 1] = 0.f;  // col 1 never written by ref
      }
    }
    // no barrier: next step's S1 writes (h1n/gh2/ogs[nxt]) are race-free vs S6
    // (ogs parity-dbuf; kqs/qwd/topd[cur]/kwhist only touched by wave 0 or
    //  behind next step's b2 which requires wave 0 to pass b1 first)
  }
}

// ---------------------------------------------------------------------------
extern "C" void kernel_launch(void* const* d_in, const int* in_sizes, int n_in,
                              void* d_out, int out_size, void* d_ws, size_t ws_size,
                              hipStream_t stream)
{
  (void)in_sizes; (void)n_in; (void)out_size; (void)ws_size;
  const float* Eq     = (const float*)d_in[0];
  const float* Ec     = (const float*)d_in[1];
  const float* Er     = (const float*)d_in[2];
  const float* W_ih1  = (const float*)d_in[3];
  const float* W_hh1  = (const float*)d_in[4];
  const float* b_ih1  = (const float*)d_in[5];
  const float* b_hh1  = (const float*)d_in[6];
  const float* W_ih2  = (const float*)d_in[7];
  const float* W_hh2  = (const float*)d_in[8];
  const float* b_ih2  = (const float*)d_in[9];
  const float* b_hh2  = (const float*)d_in[10];
  const float* Wagg   = (const float*)d_in[11];
  const float* bagg   = (const float*)d_in[12];
  const float* W_last = (const float*)d_in[13];
  const float* b_last = (const float*)d_in[14];
  const float* W_query= (const float*)d_in[15];
  const float* b_query= (const float*)d_in[16];
  const float* W_key  = (const float*)d_in[17];
  const float* b_key  = (const float*)d_in[18];
  const float* W_W    = (const float*)d_in[19];
  const float* b_W    = (const float*)d_in[20];
  const float* h1_init= (const float*)d_in[21];
  const float* h2_init= (const float*)d_in[22];
  const int* question = (const int*)d_in[23];
  const int* response = (const int*)d_in[24];
  const int* mask     = (const int*)d_in[25];
  const int* qnb      = (const int*)d_in[26];
  const int* snb      = (const int*)d_in[27];
  const int* cidx     = (const int*)d_in[28];
  const int* cmask    = (const int*)d_in[29];
  float* out = (float*)d_out;

  char* ws = (char*)d_ws;
  size_t off = 0;
  auto alloc = [&](size_t bytes) -> void* {
    void* p = ws + off;
    off += (bytes + 255) & ~(size_t)255;
    return p;
  };
  float* wih1aT = (float*)alloc(30000 * 4);
  float* erw    = (float*)alloc(600 * 4);
  float* waggT  = (float*)alloc(30000 * 4);
  float* wlastT = (float*)alloc(10000 * 4);
  float* wkeyT  = (float*)alloc(10000 * 4);
  float* scal   = (float*)alloc(4);
  u32*   wcat16 = (u32*)alloc(114688 * 4);
  float* bcat   = (float*)alloc(1792 * 4);
  float* gi1_all = (float*)alloc((size_t)B_ * T_ * 300 * 4);
  float* qw_all  = (float*)alloc((size_t)B_ * T_ * 5 * 4);
  int*   top10   = (int*)alloc((size_t)B_ * T_ * 10 * 4);

  hipLaunchKernelGGL(setupk, dim3(128), dim3(256), 0, stream,
      Er, W_ih1, b_ih1, Wagg, W_last, W_key, b_query, W_W, W_query,
      W_hh1, W_hh2, W_ih2, b_hh1, b_hh2, b_ih2,
      wih1aT, erw, waggT, wlastT, wkeyT, scal, wcat16, bcat);

  hipLaunchKernelGGL(phaseA, dim3(T_, B_), dim3(256), 0, stream,
      Eq, Ec, question, response, mask, qnb, snb,
      wih1aT, erw, waggT, wlastT, bagg, b_last, gi1_all);

  hipLaunchKernelGGL(phaseB, dim3(T_, B_), dim3(128), 0, stream,
      Eq, Ec, question, cidx, cmask, wkeyT, b_key, W_W,
      qw_all, top10);

  hipLaunchKernelGGL(seqk, dim3(B_), dim3(1024), 0, stream,
      wcat16, bcat, gi1_all, qw_all, top10, W_W, b_W,
      Eq, Ec, question, cidx, cmask,
      h1_init, h2_init, scal, out);
}

// Round 4
// 1397.228 us; speedup vs baseline: 1.6709x; 1.0727x over previous
//
#include <hip/hip_runtime.h>
#include <hip/hip_bf16.h>
#include <math.h>

typedef unsigned int u32;

#define B_ 128
#define S_ 128
#define T_ 127
#define D_ 100
#define QN_ 4
#define SN_ 4
#define KC_ 4
#define RK_ 10
#define NEGV -1000000000.0f

__device__ __forceinline__ float sigmf(float x) { return 1.0f / (1.0f + expf(-x)); }

__device__ __forceinline__ u32 f2bfbits(float x) {
  __hip_bfloat16 h = __float2bfloat16(x);
  unsigned short s;
  __builtin_memcpy(&s, &h, 2);
  return (u32)s;
}

// ---------------------------------------------------------------------------
// Setup (unchanged): transposed f32 weights for phaseA/B; erw fold;
// kw0 scalar; bf16 lane-swizzled weight image (1792 slots x 64 u32 = 256B):
//   [0,300): W_hh1 | [300,600): W_hh2 | [1024,1324): W_ih2 | [1536,1636): W_query
// slot bytes: [sub(4)][k(16 u32)], u32 k packs bf16 cols (sub*25+2k, +2k+1).
// ---------------------------------------------------------------------------
__global__ __launch_bounds__(256) void setupk(
    const float* Er, const float* W_ih1, const float* b_ih1,
    const float* Wagg, const float* W_last, const float* W_key,
    const float* b_query, const float* W_W, const float* W_query,
    const float* W_hh1, const float* W_hh2, const float* W_ih2,
    const float* b_hh1, const float* b_hh2, const float* b_ih2,
    float* wih1aT, float* erw, float* waggT, float* wlastT, float* wkeyT,
    float* scal, u32* wcat16, float* bcat)
{
  int gid = blockIdx.x * blockDim.x + threadIdx.x;
  int gsz = gridDim.x * blockDim.x;

  for (int x = gid; x < 30000; x += gsz) {
    int j = x / 300, i = x % 300;
    wih1aT[j * 300 + i] = W_ih1[i * 200 + j];
  }
  for (int x = gid; x < 600; x += gsz) {
    int r = x / 300, i = x % 300;
    float acc = b_ih1[i];
    for (int j = 0; j < 100; j++) acc += Er[r * 100 + j] * W_ih1[i * 200 + 100 + j];
    erw[x] = acc;
  }
  for (int x = gid; x < 30000; x += gsz) {
    int h = x / 10000, rr = x % 10000, j = rr / 100, i = rr % 100;
    waggT[h * 10000 + j * 100 + i] = Wagg[h * 10000 + i * 100 + j];
  }
  for (int x = gid; x < 10000; x += gsz) {
    int j = x / 100, i = x % 100;
    wlastT[j * 100 + i] = W_last[i * 100 + j];
    wkeyT[j * 100 + i] = W_key[i * 100 + j];
  }
  for (int x = gid; x < 114688; x += gsz) {
    int slot = x / 64, rem = x % 64, sbu = rem / 16, k = rem % 16;
    const float* src = nullptr;
    if (slot < 300)                       src = W_hh1 + (size_t)slot * 100;
    else if (slot < 600)                  src = W_hh2 + (size_t)(slot - 300) * 100;
    else if (slot >= 1024 && slot < 1324) src = W_ih2 + (size_t)(slot - 1024) * 100;
    else if (slot >= 1536 && slot < 1636) src = W_query + (size_t)(slot - 1536) * 100;
    u32 lo = 0, hi = 0;
    if (src) {
      int e0 = 2 * k, e1 = 2 * k + 1;
      if (e0 < 25) lo = f2bfbits(src[sbu * 25 + e0]);
      if (e1 < 25) hi = f2bfbits(src[sbu * 25 + e1]);
    }
    wcat16[x] = (hi << 16) | lo;
  }
  for (int x = gid; x < 1792; x += gsz) {
    float v = 0.f;
    if (x < 300) v = b_hh1[x];
    else if (x < 600) v = b_hh2[x - 300];
    else if (x >= 1024 && x < 1324) v = b_ih2[x - 1024];
    else if (x >= 1536 && x < 1636) v = b_query[x - 1536];
    bcat[x] = v;
  }
  if (gid == 0) {
    float acc = 0.f;  // kw of the all-zero hist state: dot(tanh(b_query), Wk_part)
    for (int i = 0; i < 100; i++) acc += tanhf(b_query[i]) * W_W[100 + i];
    scal[0] = acc;
  }
}

// ---------------------------------------------------------------------------
// Phase A (unchanged): per (b,t) 3-hop aggregate -> gi1[b,t,0:300]
// ---------------------------------------------------------------------------
__global__ __launch_bounds__(256) void phaseA(
    const float* Eq, const float* Ec, const int* question, const int* response, const int* mask,
    const int* qnb, const int* snb,
    const float* wih1aT, const float* erw, const float* waggT, const float* wlastT,
    const float* baggf, const float* blastf, float* gi1_all)
{
  const int t = blockIdx.x, b = blockIdx.y, tid = threadIdx.x;
  __shared__ float e0[100], ne0[100], e1[400], ne1[400];
  __shared__ float e2[1600], ne2[1600], m3[1600];
  __shared__ float sum4[400], sum1[100], emq[100];
  __shared__ int l1[4], l2[16], l3[64];

  const int qt = question[b * S_ + t];
  const int mt = mask[b * S_ + t];
  const int rt = response[b * S_ + t];

  if (mt != 0) {
    if (tid < 4) l1[tid] = qnb[qt * QN_ + tid];
    for (int x = tid; x < 100; x += 256) e0[x] = Eq[(size_t)qt * 100 + x];
    __syncthreads();
    if (tid < 16) l2[tid] = snb[l1[tid >> 2] * SN_ + (tid & 3)];
    for (int x = tid; x < 400; x += 256) e1[x] = Ec[(size_t)l1[x / 100] * 100 + (x % 100)];
    __syncthreads();
    if (tid < 64) l3[tid] = qnb[l2[tid >> 2] * QN_ + (tid & 3)];
    for (int x = tid; x < 1600; x += 256) e2[x] = Eq[(size_t)l2[x / 100] * 100 + (x % 100)];
    __syncthreads();
    for (int x = tid; x < 1600; x += 256) {
      int r = x / 100, j = x % 100;
      const int* lr = l3 + r * 4;
      float s = Ec[(size_t)lr[0] * 100 + j] + Ec[(size_t)lr[1] * 100 + j] +
                Ec[(size_t)lr[2] * 100 + j] + Ec[(size_t)lr[3] * 100 + j];
      m3[x] = e2[x] + 0.25f * s;
    }
    for (int x = tid; x < 100; x += 256)
      sum1[x] = e0[x] + 0.25f * (e1[x] + e1[100 + x] + e1[200 + x] + e1[300 + x]);
    for (int x = tid; x < 400; x += 256) {
      int k = x / 100, j = x % 100;
      const float* e2k = e2 + k * 400;
      sum4[x] = e1[x] + 0.25f * (e2k[j] + e2k[100 + j] + e2k[200 + j] + e2k[300 + j]);
    }
    __syncthreads();
    for (int o = tid; o < 2100; o += 256) {
      const float *in, *W;
      float bia;
      float* dst;
      int i = o % 100;
      if (o < 100)      { in = sum1;                           W = waggT;          bia = baggf[i];       dst = ne0 + o; }
      else if (o < 500) { in = sum4 + ((o - 100) / 100) * 100; W = waggT + 10000;  bia = baggf[100 + i]; dst = ne1 + (o - 100); }
      else              { in = m3 + ((o - 500) / 100) * 100;   W = waggT + 20000;  bia = baggf[200 + i]; dst = ne2 + (o - 500); }
      float acc = bia;
      for (int j = 0; j < 100; j++) acc += in[j] * W[j * 100 + i];
      *dst = tanhf(acc);
    }
    __syncthreads();
    for (int x = tid; x < 100; x += 256)
      sum1[x] = ne0[x] + 0.25f * (ne1[x] + ne1[100 + x] + ne1[200 + x] + ne1[300 + x]);
    for (int x = tid; x < 400; x += 256) {
      int k = x / 100, j = x % 100;
      const float* n2k = ne2 + k * 400;
      sum4[x] = ne1[x] + 0.25f * (n2k[j] + n2k[100 + j] + n2k[200 + j] + n2k[300 + j]);
    }
    __syncthreads();
    for (int o = tid; o < 500; o += 256) {
      int i = o % 100;
      if (o < 100) {
        float acc = baggf[i];
        for (int j = 0; j < 100; j++) acc += sum1[j] * waggT[j * 100 + i];
        e0[i] = tanhf(acc);
      } else {
        const float* in = sum4 + ((o - 100) / 100) * 100;
        float acc = baggf[100 + i];
        for (int j = 0; j < 100; j++) acc += in[j] * waggT[10000 + j * 100 + i];
        e1[o - 100] = tanhf(acc);
      }
    }
    __syncthreads();
    for (int x = tid; x < 100; x += 256)
      sum1[x] = e0[x] + 0.25f * (e1[x] + e1[100 + x] + e1[200 + x] + e1[300 + x]);
    __syncthreads();
    for (int o = tid; o < 100; o += 256) {
      float acc = baggf[o];
      for (int j = 0; j < 100; j++) acc += sum1[j] * waggT[j * 100 + o];
      ne0[o] = tanhf(acc);
    }
    __syncthreads();
    for (int o = tid; o < 100; o += 256) {
      float acc = blastf[o];
      for (int j = 0; j < 100; j++) acc += ne0[j] * wlastT[j * 100 + o];
      emq[o] = tanhf(acc);
    }
    __syncthreads();
  } else {
    for (int x = tid; x < 100; x += 256) emq[x] = Eq[(size_t)qt * 100 + x];
    __syncthreads();
  }

  const size_t bt = (size_t)b * T_ + t;
  for (int o = tid; o < 300; o += 256) {
    float acc = erw[rt * 300 + o];
    for (int j = 0; j < 100; j++) acc += emq[j] * wih1aT[j * 300 + o];
    gi1_all[bt * 300 + o] = acc;
  }
}

// ---------------------------------------------------------------------------
// Phase B (unchanged): qw[5] and top-10 indices per (b,t).
// ---------------------------------------------------------------------------
__global__ __launch_bounds__(128) void phaseB(
    const float* Eq, const float* Ec, const int* question, const int* cidx, const int* cmask,
    const float* wkeyT, const float* b_key, const float* W_W,
    float* qw_all, int* top10_all)
{
  const int t = blockIdx.x, b = blockIdx.y, tid = threadIdx.x;
  const size_t bt = (size_t)b * T_ + t;
  __shared__ float qcf[500];
  __shared__ float qtl[500];
  __shared__ float qwp[20];
  __shared__ float orig[128];
  __shared__ float sval[128];
  __shared__ int sidx[128];
  __shared__ int ci[4], cm[4];

  const int qn = question[b * S_ + t + 1];
  if (tid < 4) { ci[tid] = cidx[qn * KC_ + tid]; cm[tid] = cmask[qn * KC_ + tid]; }
  __syncthreads();

  for (int u = tid; u < 500; u += 128) {
    int row = u / 100, j = u % 100;
    float v;
    if (row == 0) v = Eq[(size_t)qn * 100 + j];
    else {
      int k = row - 1;
      v = cm[k] ? Ec[(size_t)ci[k] * 100 + j] : 0.f;
    }
    qcf[u] = v;
  }
  __syncthreads();
  for (int o = tid; o < 500; o += 128) {
    int q = o / 100, i = o % 100;
    float acc = b_key[i];
    const float* src = qcf + q * 100;
    for (int j = 0; j < 100; j++) acc += src[j] * wkeyT[j * 100 + i];
    qtl[o] = tanhf(acc);
  }
  __syncthreads();
  if (tid < 20) {
    int q = tid / 4, part = tid % 4;
    float acc = 0.f;
    for (int j = part * 25; j < part * 25 + 25; j++) acc += qtl[q * 100 + j] * W_W[j];
    qwp[tid] = acc;
  }
  __syncthreads();
  if (tid < 5) qw_all[bt * 5 + tid] = qwp[tid * 4] + qwp[tid * 4 + 1] + qwp[tid * 4 + 2] + qwp[tid * 4 + 3];

  if (t > RK_) {
    float sc = -__builtin_inff();
    if (tid < t) {
      int qs = question[b * S_ + tid];
      float acc = 0.f;
      for (int j = 0; j < 100; j++) acc += Eq[(size_t)qs * 100 + j] * qcf[j];
      sc = acc;
    }
    orig[tid] = sc;
    __syncthreads();
    for (int pass = 0; pass < 10; pass++) {
      sval[tid] = orig[tid];
      sidx[tid] = tid;
      __syncthreads();
      for (int offt = 64; offt > 0; offt >>= 1) {
        if (tid < offt) {
          float v2 = sval[tid + offt];
          int i2 = sidx[tid + offt];
          if (v2 > sval[tid] || (v2 == sval[tid] && i2 < sidx[tid])) { sval[tid] = v2; sidx[tid] = i2; }
        }
        __syncthreads();
      }
      if (tid == 0) top10_all[bt * 10 + pass] = sidx[0];
      if (tid == sidx[0]) orig[tid] = -__builtin_inff();
      __syncthreads();
    }
  }
}

// bf16 row-dot helper: dot(unpack(w[0..3]), hr[0..31])
__device__ __forceinline__ float bf16_dot32(const uint4 w[4], const float hr[32]) {
  float a = 0.f;
#pragma unroll
  for (int c = 0; c < 4; ++c) {
    uint4 ww = w[c];
    const int e = c * 8;
    a = fmaf(__uint_as_float(ww.x << 16),         hr[e + 0], a);
    a = fmaf(__uint_as_float(ww.x & 0xffff0000u), hr[e + 1], a);
    a = fmaf(__uint_as_float(ww.y << 16),         hr[e + 2], a);
    a = fmaf(__uint_as_float(ww.y & 0xffff0000u), hr[e + 3], a);
    a = fmaf(__uint_as_float(ww.z << 16),         hr[e + 4], a);
    a = fmaf(__uint_as_float(ww.z & 0xffff0000u), hr[e + 5], a);
    a = fmaf(__uint_as_float(ww.w << 16),         hr[e + 6], a);
    a = fmaf(__uint_as_float(ww.w & 0xffff0000u), hr[e + 7], a);
  }
  return a;
}

// ---------------------------------------------------------------------------
// Sequential scan v12: 1024 threads, 3 barriers/step.
// Change vs v11 (788us): W_hh1 -> LDS too (S1 L2 stream halved 153.6->76.8
// KB/step). To make room, g2hist moves to a GLOBAL workspace buffer (only
// 10 rows = 4KB/step are read, data-dependent; rows padded to 128 floats so
// no cacheline straddles rows -> no L1 same-CU staleness hazard; write->read
// separated by the vmcnt(0)-draining barrier). bresS compacted 1792->1000.
// LDS total 160.7 KB. Wave-role balance: S1 = pure {W_hh1-LDS | W_hh2-stream}
// waves (no mixed heavy wave); og s>=1 dots moved from S1 to S3 on waves
// that were idle there. All dot accumulation orders unchanged -> numerics
// bit-identical.
// Phases:
//   S1: Whh1(LDS) 3-dot+GRU1->h1n [grp<100] | Whh2(L2) 3-dot->gh2 [grp 128-228) -> b1
//   S3: Wih2(LDS) 3-dot+GRU2->g2v [grp<100] | h1 copy [tid 400-500) | og s>=1 [grp 128-178) -> b2
//   S5: kq(LDS) | og s=0 | commits + h2/g2hist updates -> b3
//   S6: wave-0 kw/softmax/store (no trailing barrier; ogs dbuf by parity)
// ---------------------------------------------------------------------------
__global__ __launch_bounds__(1024) void seqk(
    const u32* __restrict__ wcat16, const float* __restrict__ bcat,
    const float* __restrict__ gi1_all, const float* __restrict__ qw_all, const int* __restrict__ top10_all,
    const float* __restrict__ W_W, const float* __restrict__ b_W,
    const float* __restrict__ Eq, const float* __restrict__ Ec, const int* __restrict__ question,
    const int* __restrict__ cidx, const int* __restrict__ cmask,
    const float* __restrict__ h1_init, const float* __restrict__ h2_init, const float* __restrict__ scal,
    float* __restrict__ g2hist_g, float* __restrict__ out)
{
  const int b = blockIdx.x, tid = threadIdx.x;
  const int grp = tid >> 2, sub = tid & 3;  // grp in [0,256)
  const int ptid = tid - 424;               // prefetch lane index
  const uint4* wimg = (const uint4*)wcat16;
  float* const g2h = g2hist_g + (size_t)b * (T_ * 128);  // rows stride 128

  __shared__ float hcomb[200];         // h1 | h2
  __shared__ __align__(16) float h1n[100], g2v[100];
  __shared__ float gh2[300], kqs[100];
  __shared__ float gi1d[2][300];
  __shared__ float qcd[2][500];
  __shared__ float qwd[2][5];
  __shared__ int topd[2][10];
  __shared__ float kwhist[128];
  __shared__ float ogs[2][55];
  __shared__ float bresS[1000];        // [0,600) b_hh1|b_hh2, [600,900) b_ih2, [900,1000) b_query
  __shared__ float wkS[100];
  __shared__ int cidS[8], cid0S[8];
  __shared__ int qn1S, qnS;
  __shared__ u32 whh1S[300 * 52];      // 62.4 KB: W_hh1,   packed [row][sub(4)][13 u32]
  __shared__ u32 wih2S[300 * 52];      // 62.4 KB: W_ih2,   packed [row][sub(4)][13 u32]
  __shared__ u32 wqS[100 * 52];        // 20.8 KB: W_query, packed [row][sub(4)][13 u32]

  for (int x = tid; x < 1000; x += 1024) {
    int src = (x < 600) ? x : ((x < 900) ? (1024 + (x - 600)) : (1536 + (x - 900)));
    bresS[x] = bcat[src];
  }
  if (tid < 100) wkS[tid] = W_W[100 + tid];

  // one-time LDS packs: W_hh1 slots [0,300), W_ih2 slots [1024,1324), W_query [1536,1636)
  for (int x = tid; x < 300 * 52; x += 1024) {
    int s = x / 52, r = x - s * 52;
    int sb = r / 13, k = r - sb * 13;
    whh1S[x] = wcat16[(size_t)s * 64 + sb * 16 + k];
    wih2S[x] = wcat16[(size_t)(1024 + s) * 64 + sb * 16 + k];
  }
  for (int x = tid; x < 100 * 52; x += 1024) {
    int s = x / 52, r = x - s * 52;
    int sb = r / 13, k = r - sb * 13;
    wqS[x] = wcat16[(size_t)(1536 + s) * 64 + sb * 16 + k];
  }

  const float bWv = b_W[0];
  const float kw0 = scal[0];

  if (tid < 100) {
    hcomb[tid] = h1_init[b * 100 + tid];
  } else if (tid < 200) {
    hcomb[tid] = h2_init[b * 100 + (tid - 100)];
  }
  if (tid >= 200 && tid < 328) g2h[tid - 200] = 0.f;  // row 0 of g2hist = zeros
  if (tid < 128) kwhist[tid] = kw0;
  if (tid < 300) gi1d[0][tid] = gi1_all[(size_t)b * T_ * 300 + tid];
  if (tid >= 300 && tid < 305) qwd[0][tid - 300] = qw_all[(size_t)b * T_ * 5 + (tid - 300)];
  if (tid == 306) { qn1S = question[b * S_ + 2]; qnS = question[b * S_ + 3]; }
  if (tid >= 320 && tid < 328) {
    int k = tid - 320, qn0 = question[b * S_ + 1];
    cid0S[k] = (k < 4) ? cidx[qn0 * KC_ + k] : cmask[qn0 * KC_ + k - 4];
  }
  if (tid >= 328 && tid < 336) {
    int k = tid - 328, qn1 = question[b * S_ + 2];
    cidS[k] = (k < 4) ? cidx[qn1 * KC_ + k] : cmask[qn1 * KC_ + k - 4];
  }
  __syncthreads();
  if (tid < 500) {
    int q = tid / 100, j = tid % 100;
    int qn0 = question[b * S_ + 1];
    qcd[0][tid] = (q == 0) ? Eq[(size_t)qn0 * 100 + j]
                           : (cid0S[4 + q - 1] ? Ec[(size_t)cid0S[q - 1] * 100 + j] : 0.f);
  }
  __syncthreads();

  for (int t = 0; t < T_; ++t) {
    const size_t bt = (size_t)b * T_ + t;
    const int cur = t & 1, nxt = cur ^ 1;
    const bool pf = (t + 1) < T_;
    const int qn1 = qn1S, qn2 = qnS;  // stable (committed prior S5, barrier since)

    // ---- TOP: issue ALL t+1 prefetch on tids >= 424 (latency hides under S1) ----
    float pqc = 0.f, pgi = 0.f, pqw = 0.f;
    int ptop = 0, pci = 0, pqn = 0;
    if (pf) {
      if (ptid >= 0 && ptid < 500) {
        int q = ptid / 100, j = ptid % 100;
        pqc = (q == 0) ? Eq[(size_t)qn1 * 100 + j]
                       : (cidS[4 + q - 1] ? Ec[(size_t)cidS[q - 1] * 100 + j] : 0.f);
      }
      if (ptid >= 0 && ptid < 300) pgi = gi1_all[(bt + 1) * 300 + ptid];
      if (tid >= 924 && tid < 929) pqw = qw_all[(bt + 1) * 5 + (tid - 924)];
      if (tid >= 929 && tid < 939 && (t + 1) > RK_) ptop = top10_all[(bt + 1) * 10 + (tid - 929)];
      if (tid >= 939 && tid < 947 && (t + 2) < T_) {
        int k = tid - 939;
        pci = (k < 4) ? cidx[qn2 * KC_ + k] : cmask[qn2 * KC_ + k - 4];
      }
      if (tid == 947) pqn = question[b * S_ + min(t + 4, S_ - 1)];
    }

    // ---- S1: Whh1(LDS)+GRU1 -> h1n [grp<100] | Whh2(L2) -> gh2 [grp 128-228) ----
    if (grp < 100) {
      const int j = grp;
      const u32* wr0 = whh1S + j * 52 + sub * 13;
      const u32* wr1 = wr0 + 100 * 52;
      const u32* wr2 = wr0 + 200 * 52;
      const float* hsrc = hcomb + sub * 25;
      float a0 = 0.f, a1 = 0.f, a2 = 0.f;
#pragma unroll
      for (int k = 0; k < 13; ++k) {
        float h0  = hsrc[2 * k];
        float h1v = (2 * k + 1 < 25) ? hsrc[2 * k + 1] : 0.f;
        u32 w0v = wr0[k], w1v = wr1[k], w2v = wr2[k];
        a0 = fmaf(__uint_as_float(w0v << 16),         h0,  a0);
        a0 = fmaf(__uint_as_float(w0v & 0xffff0000u), h1v, a0);
        a1 = fmaf(__uint_as_float(w1v << 16),         h0,  a1);
        a1 = fmaf(__uint_as_float(w1v & 0xffff0000u), h1v, a1);
        a2 = fmaf(__uint_as_float(w2v << 16),         h0,  a2);
        a2 = fmaf(__uint_as_float(w2v & 0xffff0000u), h1v, a2);
      }
      a0 += __shfl_xor(a0, 1); a0 += __shfl_xor(a0, 2);
      a1 += __shfl_xor(a1, 1); a1 += __shfl_xor(a1, 2);
      a2 += __shfl_xor(a2, 1); a2 += __shfl_xor(a2, 2);
      if (sub == 0) {
        float g0 = a0 + bresS[j], gg1 = a1 + bresS[100 + j], gg2 = a2 + bresS[200 + j];
        float rg = sigmf(gi1d[cur][j] + g0);
        float z  = sigmf(gi1d[cur][100 + j] + gg1);
        float n  = tanhf(gi1d[cur][200 + j] + rg * gg2);
        h1n[j] = (1.f - z) * n + z * hcomb[j];
      }
    } else if (grp >= 128 && grp < 228) {
      const int j = grp - 128;
      const int s0 = 300 + j;
      uint4 w0[4], w1[4], w2[4];
      {
        const uint4* p0 = wimg + (size_t)s0 * 16 + sub * 4;
        const uint4* p1 = wimg + (size_t)(s0 + 100) * 16 + sub * 4;
        const uint4* p2 = wimg + (size_t)(s0 + 200) * 16 + sub * 4;
#pragma unroll
        for (int c = 0; c < 4; ++c) { w0[c] = p0[c]; w1[c] = p1[c]; w2[c] = p2[c]; }
      }
      float hr[32];
#pragma unroll
      for (int c = 25; c < 32; ++c) hr[c] = 0.f;
#pragma unroll
      for (int c = 0; c < 25; ++c) hr[c] = hcomb[100 + sub * 25 + c];
      float a0 = bf16_dot32(w0, hr);
      float a1 = bf16_dot32(w1, hr);
      float a2 = bf16_dot32(w2, hr);
      a0 += __shfl_xor(a0, 1); a0 += __shfl_xor(a0, 2);
      a1 += __shfl_xor(a1, 1); a1 += __shfl_xor(a1, 2);
      a2 += __shfl_xor(a2, 1); a2 += __shfl_xor(a2, 2);
      if (sub == 0) {
        gh2[j]       = a0 + bresS[300 + j];
        gh2[100 + j] = a1 + bresS[400 + j];
        gh2[200 + j] = a2 + bresS[500 + j];
      }
    }
    __syncthreads();  // b1: h1n, gh2 visible

    // ---- S3: Wih2(LDS)+GRU2 -> g2v [grp<100] | h1 copy | og s>=1 [grp 128-178) ----
    if (grp < 100) {
      const int j = grp;
      const u32* wr0 = wih2S + j * 52 + sub * 13;
      const u32* wr1 = wr0 + 100 * 52;
      const u32* wr2 = wr0 + 200 * 52;
      const float* hsrc = h1n + sub * 25;
      float a0 = 0.f, a1 = 0.f, a2 = 0.f;
#pragma unroll
      for (int k = 0; k < 13; ++k) {
        float h0  = hsrc[2 * k];
        float h1v = (2 * k + 1 < 25) ? hsrc[2 * k + 1] : 0.f;
        u32 w0v = wr0[k], w1v = wr1[k], w2v = wr2[k];
        a0 = fmaf(__uint_as_float(w0v << 16),         h0,  a0);
        a0 = fmaf(__uint_as_float(w0v & 0xffff0000u), h1v, a0);
        a1 = fmaf(__uint_as_float(w1v << 16),         h0,  a1);
        a1 = fmaf(__uint_as_float(w1v & 0xffff0000u), h1v, a1);
        a2 = fmaf(__uint_as_float(w2v << 16),         h0,  a2);
        a2 = fmaf(__uint_as_float(w2v & 0xffff0000u), h1v, a2);
      }
      a0 += __shfl_xor(a0, 1); a0 += __shfl_xor(a0, 2);
      a1 += __shfl_xor(a1, 1); a1 += __shfl_xor(a1, 2);
      a2 += __shfl_xor(a2, 1); a2 += __shfl_xor(a2, 2);
      if (sub == 0) {
        float i_r = a0 + bresS[600 + j], i_z = a1 + bresS[700 + j], i_n = a2 + bresS[800 + j];
        float rg = sigmf(i_r + gh2[j]);
        float z  = sigmf(i_z + gh2[100 + j]);
        float n  = tanhf(i_n + rg * gh2[200 + j]);
        g2v[j] = (1.f - z) * n + z * hcomb[100 + j];
      }
    } else if (tid >= 400 && tid < 500) {
      hcomb[tid - 400] = h1n[tid - 400];  // h1 <- h1n (h1n visible after b1)
    } else if (grp >= 128 && grp < 178) {
      int d = grp - 128;  // 0..49
      int s = 1 + d / 5, q = d % 5;
      bool valid = (t > RK_) || (s - 1 < t);
      float a = 0.f;
      if (valid) {
        int idx = (t > RK_) ? topd[cur][s - 1] : (s - 1);
        const float* qcr = &qcd[cur][q * 100 + sub * 25];
        const float* hrow = g2h + (size_t)idx * 128 + sub * 25;
#pragma unroll
        for (int c = 0; c < 25; ++c) a = fmaf(qcr[c], hrow[c], a);
      }
      a += __shfl_xor(a, 1);
      a += __shfl_xor(a, 2);
      if (sub == 0) ogs[cur][s * 5 + q] = a;
    }
    __syncthreads();  // b2: g2v, ogs[cur][5..54] visible

    // ---- S5: kq (grp<100, W_query from LDS) | og s=0 (grp<105) | commits (tid>=424) ----
    if (grp < 100) {
      const u32* wq = wqS + grp * 52 + sub * 13;
      const float* hsrc = g2v + sub * 25;
      float a = 0.f;
#pragma unroll
      for (int k = 0; k < 13; ++k) {
        float h0  = hsrc[2 * k];
        float h1v = (2 * k + 1 < 25) ? hsrc[2 * k + 1] : 0.f;
        u32 wv = wq[k];
        a = fmaf(__uint_as_float(wv << 16),         h0,  a);
        a = fmaf(__uint_as_float(wv & 0xffff0000u), h1v, a);
      }
      a += __shfl_xor(a, 1);
      a += __shfl_xor(a, 2);
      if (sub == 0) kqs[grp] = tanhf(a + bresS[900 + grp]) * wkS[grp];
    } else if (grp < 105) {
      int q = grp - 100;
      const float* qcr = &qcd[cur][q * 100 + sub * 25];
      float a = 0.f;
#pragma unroll
      for (int c = 0; c < 25; ++c) a = fmaf(qcr[c], g2v[sub * 25 + c], a);
      a += __shfl_xor(a, 1);
      a += __shfl_xor(a, 2);
      if (sub == 0) ogs[cur][q] = a;
    }
    if (ptid >= 0) {
      if (pf) {
        if (ptid < 500) qcd[nxt][ptid] = pqc;
        if (ptid < 300) gi1d[nxt][ptid] = pgi;
        if (tid >= 924 && tid < 929) qwd[nxt][tid - 924] = pqw;
        if (tid >= 929 && tid < 939 && (t + 1) > RK_) topd[nxt][tid - 929] = min(T_ - 1, max(0, ptop));
        if (tid >= 939 && tid < 947 && (t + 2) < T_) cidS[tid - 939] = pci;
        if (tid == 947) { qn1S = qn2; qnS = pqn; }
      }
      if (t > 0 && ptid < 100) {
        hcomb[100 + ptid] = g2v[ptid];
        g2h[(size_t)t * 128 + ptid] = g2v[ptid];
      }
    }
    __syncthreads();  // b3: kqs, ogs, commits, state updates visible (vmcnt drained)

    // ---- S6: wave-0 kw reduce + softmax + store (no trailing barrier) ----
    if (tid < 64) {
      float v = (tid < 50) ? (kqs[tid] + kqs[tid + 50]) : 0.f;
      v += __shfl_xor(v, 1);
      v += __shfl_xor(v, 2);
      v += __shfl_xor(v, 4);
      v += __shfl_xor(v, 8);
      v += __shfl_xor(v, 16);
      v += __shfl_xor(v, 32);
      const float kw = v;  // all 64 lanes
      float pq = 0.f;
      if (tid < 5) {
        const float qw = qwd[cur][tid];
        float tmp[11];
        float m = -__builtin_inff();
#pragma unroll
        for (int s = 0; s < 11; ++s) {
          float kws;
          bool valid;
          if (s == 0) { kws = kw; valid = true; }
          else if (t > RK_) { kws = kwhist[topd[cur][s - 1]]; valid = true; }
          else { valid = (s - 1 < t); kws = kwhist[s - 1]; }
          float tv = valid ? (qw + kws + bWv) : NEGV;
          tmp[s] = tv;
          m = fmaxf(m, tv);
        }
        float den = 0.f, num = 0.f;
#pragma unroll
        for (int s = 0; s < 11; ++s) {
          float e = expf(tmp[s] - m);
          den += e;
          num += e * ogs[cur][s * 5 + tid];
        }
        pq = num / den;
      }
      if (tid == 5 && t > 0) kwhist[t] = kw;  // read only by wave 0 (program order)
      float sp = pq;
      sp += __shfl_xor(sp, 1);
      sp += __shfl_xor(sp, 2);
      sp += __shfl_xor(sp, 4);
      if (tid == 0) {
        int col = (t == 0) ? 0 : (t + 1);
        out[b * S_ + col] = sp;
        if (t == 0) out[b * S_ + 1] = 0.f;  // col 1 never written by ref
      }
    }
    // no barrier: next step's S1 writes (h1n/gh2) aren't read by S6; ogs is
    // parity-dbuf and now written in S3 (behind b1, which wave 0 must reach
    // after finishing S6); kqs/qwd/topd[cur]/kwhist only touched by wave 0
    // or behind barriers that require wave 0's progress.
  }
}

// ---------------------------------------------------------------------------
extern "C" void kernel_launch(void* const* d_in, const int* in_sizes, int n_in,
                              void* d_out, int out_size, void* d_ws, size_t ws_size,
                              hipStream_t stream)
{
  (void)in_sizes; (void)n_in; (void)out_size; (void)ws_size;
  const float* Eq     = (const float*)d_in[0];
  const float* Ec     = (const float*)d_in[1];
  const float* Er     = (const float*)d_in[2];
  const float* W_ih1  = (const float*)d_in[3];
  const float* W_hh1  = (const float*)d_in[4];
  const float* b_ih1  = (const float*)d_in[5];
  const float* b_hh1  = (const float*)d_in[6];
  const float* W_ih2  = (const float*)d_in[7];
  const float* W_hh2  = (const float*)d_in[8];
  const float* b_ih2  = (const float*)d_in[9];
  const float* b_hh2  = (const float*)d_in[10];
  const float* Wagg   = (const float*)d_in[11];
  const float* bagg   = (const float*)d_in[12];
  const float* W_last = (const float*)d_in[13];
  const float* b_last = (const float*)d_in[14];
  const float* W_query= (const float*)d_in[15];
  const float* b_query= (const float*)d_in[16];
  const float* W_key  = (const float*)d_in[17];
  const float* b_key  = (const float*)d_in[18];
  const float* W_W    = (const float*)d_in[19];
  const float* b_W    = (const float*)d_in[20];
  const float* h1_init= (const float*)d_in[21];
  const float* h2_init= (const float*)d_in[22];
  const int* question = (const int*)d_in[23];
  const int* response = (const int*)d_in[24];
  const int* mask     = (const int*)d_in[25];
  const int* qnb      = (const int*)d_in[26];
  const int* snb      = (const int*)d_in[27];
  const int* cidx     = (const int*)d_in[28];
  const int* cmask    = (const int*)d_in[29];
  float* out = (float*)d_out;

  char* ws = (char*)d_ws;
  size_t off = 0;
  auto alloc = [&](size_t bytes) -> void* {
    void* p = ws + off;
    off += (bytes + 255) & ~(size_t)255;
    return p;
  };
  float* wih1aT = (float*)alloc(30000 * 4);
  float* erw    = (float*)alloc(600 * 4);
  float* waggT  = (float*)alloc(30000 * 4);
  float* wlastT = (float*)alloc(10000 * 4);
  float* wkeyT  = (float*)alloc(10000 * 4);
  float* scal   = (float*)alloc(4);
  u32*   wcat16 = (u32*)alloc(114688 * 4);
  float* bcat   = (float*)alloc(1792 * 4);
  float* gi1_all = (float*)alloc((size_t)B_ * T_ * 300 * 4);
  float* qw_all  = (float*)alloc((size_t)B_ * T_ * 5 * 4);
  int*   top10   = (int*)alloc((size_t)B_ * T_ * 10 * 4);
  float* g2h     = (float*)alloc((size_t)B_ * T_ * 128 * 4);

  hipLaunchKernelGGL(setupk, dim3(128), dim3(256), 0, stream,
      Er, W_ih1, b_ih1, Wagg, W_last, W_key, b_query, W_W, W_query,
      W_hh1, W_hh2, W_ih2, b_hh1, b_hh2, b_ih2,
      wih1aT, erw, waggT, wlastT, wkeyT, scal, wcat16, bcat);

  hipLaunchKernelGGL(phaseA, dim3(T_, B_), dim3(256), 0, stream,
      Eq, Ec, question, response, mask, qnb, snb,
      wih1aT, erw, waggT, wlastT, bagg, b_last, gi1_all);

  hipLaunchKernelGGL(phaseB, dim3(T_, B_), dim3(128), 0, stream,
      Eq, Ec, question, cidx, cmask, wkeyT, b_key, W_W,
      qw_all, top10);

  hipLaunchKernelGGL(seqk, dim3(B_), dim3(1024), 0, stream,
      wcat16, bcat, gi1_all, qw_all, top10, W_W, b_W,
      Eq, Ec, question, cidx, cmask,
      h1_init, h2_init, scal, g2h, out);
}